// Round 4
// baseline (729.056 us; speedup 1.0000x reference)
//
#include <hip/hip_runtime.h>
#include <stdint.h>

// EncoderLayer on MI355X (gfx950), bf16 MFMA pipeline.
// B=4, S=2048, HID=1024, HEADS=16, HD=64, PF=4096. M = B*S = 8192.

typedef __bf16 bf16;
typedef __bf16 bf16x4 __attribute__((ext_vector_type(4)));
typedef __bf16 bf16x8 __attribute__((ext_vector_type(8)));
typedef short  s16x4  __attribute__((ext_vector_type(4)));
typedef float  f32x4  __attribute__((ext_vector_type(4)));

__device__ __forceinline__ bf16 f2b(float x){
  uint32_t u = __builtin_bit_cast(uint32_t, x);
  uint32_t r = (u + 0x7FFFu + ((u >> 16) & 1u)) >> 16;   // RNE
  return __builtin_bit_cast(bf16, (uint16_t)r);
}

__device__ __forceinline__ float ex2(float x){
#if __has_builtin(__builtin_amdgcn_exp2f)
  return __builtin_amdgcn_exp2f(x);
#else
  return __exp2f(x);
#endif
}

// 16x16x16 bf16 MFMA (A,B: 4 bf16 / 2 VGPRs each; D: 4 f32)
__device__ __forceinline__ f32x4 mfma16bf(bf16x4 a, bf16x4 b, f32x4 c){
#if __has_builtin(__builtin_amdgcn_mfma_f32_16x16x16_bf16)
  return __builtin_amdgcn_mfma_f32_16x16x16_bf16(a, b, c, 0, 0, 0);
#elif __has_builtin(__builtin_amdgcn_mfma_f32_16x16x16bf16_1k)
  return __builtin_amdgcn_mfma_f32_16x16x16bf16_1k(
      __builtin_bit_cast(s16x4, a), __builtin_bit_cast(s16x4, b), c, 0, 0, 0);
#else
  f32x4 d = c;
  asm volatile("v_mfma_f32_16x16x16_bf16 %0, %1, %2, %0"
               : "+v"(d)
               : "v"(__builtin_bit_cast(s16x4, a)), "v"(__builtin_bit_cast(s16x4, b)));
  return d;
#endif
}

// ---------------- cast f32 -> bf16 (vectorized) ----------------
__global__ __launch_bounds__(256) void castb_kernel(const float* __restrict__ in,
                                                    bf16* __restrict__ out, int n4){
  const int i = blockIdx.x*256 + threadIdx.x;
  if (i >= n4) return;
  const float4 v = ((const float4*)in)[i];
  bf16x4 u = { f2b(v.x), f2b(v.y), f2b(v.z), f2b(v.w) };
  *(bf16x4*)(out + (size_t)i*4) = u;
}

// ---------------- transpose+cast W[K][N] f32 -> Wt[N][K] bf16 ----------------
__global__ void transcast_kernel(const float* __restrict__ W, bf16* __restrict__ Wt,
                                 int K, int N){
  __shared__ float t[32][33];
  const int x = threadIdx.x, y = threadIdx.y;           // (32,8)
  const int n0 = blockIdx.x*32, k0 = blockIdx.y*32;
  #pragma unroll
  for (int r=0;r<4;r++) t[y+8*r][x] = W[(size_t)(k0+y+8*r)*N + n0+x];
  __syncthreads();
  #pragma unroll
  for (int r=0;r<4;r++) Wt[(size_t)(n0+y+8*r)*K + k0+x] = f2b(t[x][y+8*r]);
}

// ---------------- GEMM: C = A[M][K] * Bt[N][K]^T + bias ----------------
// 128x128 tile, 4 waves (2x2), wave = 64x64 = 4x4 frags of 16x16x32 MFMA.
// Reg-staged LDS with next-K-tile register prefetch (known-good 834 TF).
// LDS [128][32] bf16, 16B-slot XOR swizzle slot^=(row>>1)&3.
// OMODE: 0=f32, 1=bf16 (scaled by oscale), 2=bf16+swish,
//        3=bf16 V-transposed [b*1024+col][2048]
template<int OMODE>
__global__ __launch_bounds__(256) void gemm_bt_kernel(
    const bf16* __restrict__ A, const bf16* __restrict__ Bt,
    const float* __restrict__ bias, void* __restrict__ C,
    int M, int N, int K, float oscale)
{
  __shared__ bf16 As[128*32];
  __shared__ bf16 Bs[128*32];
  const int tid = threadIdx.x;
  const int w = tid >> 6, lane = tid & 63;
  const int wr = w >> 1, wc = w & 1;
  const int g16 = lane >> 4, l16 = lane & 15;
  const int m0 = blockIdx.y*128, n0 = blockIdx.x*128;

  const int ar = tid >> 2, asl = tid & 3;
  const bf16* gA = A  + (size_t)(m0+ar)*K + asl*8;
  const bf16* gB = Bt + (size_t)(n0+ar)*K + asl*8;
  const int sw0 = (ar>>1)&3;
  const int la = ar*32      + ((asl ^ sw0)<<3);
  const int lb = (ar+64)*32 + ((asl ^ sw0)<<3);

  f32x4 acc[4][4];
  const f32x4 fz = {0.f,0.f,0.f,0.f};
  #pragma unroll
  for (int m=0;m<4;m++)
    #pragma unroll
    for (int n=0;n<4;n++) acc[m][n] = fz;

  bf16x8 ra0 = *(const bf16x8*)gA;
  bf16x8 ra1 = *(const bf16x8*)(gA + (size_t)64*K);
  bf16x8 rb0 = *(const bf16x8*)gB;
  bf16x8 rb1 = *(const bf16x8*)(gB + (size_t)64*K);

  for (int k0=0; k0<K; k0+=32){
    __syncthreads();
    *(bf16x8*)&As[la] = ra0;
    *(bf16x8*)&As[lb] = ra1;
    *(bf16x8*)&Bs[la] = rb0;
    *(bf16x8*)&Bs[lb] = rb1;
    __syncthreads();
    if (k0 + 32 < K){
      ra0 = *(const bf16x8*)(gA + k0+32);
      ra1 = *(const bf16x8*)(gA + (size_t)64*K + k0+32);
      rb0 = *(const bf16x8*)(gB + k0+32);
      rb1 = *(const bf16x8*)(gB + (size_t)64*K + k0+32);
    }
    bf16x8 af[4], bfv[4];
    #pragma unroll
    for (int m=0;m<4;m++){
      const int r = wr*64 + m*16 + l16;
      af[m] = *(const bf16x8*)&As[r*32 + ((g16 ^ ((r>>1)&3))<<3)];
    }
    #pragma unroll
    for (int n=0;n<4;n++){
      const int r = wc*64 + n*16 + l16;
      bfv[n] = *(const bf16x8*)&Bs[r*32 + ((g16 ^ ((r>>1)&3))<<3)];
    }
    #pragma unroll
    for (int m=0;m<4;m++)
      #pragma unroll
      for (int n=0;n<4;n++)
        acc[m][n] = __builtin_amdgcn_mfma_f32_16x16x32_bf16(af[m], bfv[n], acc[m][n], 0, 0, 0);
  }

  // epilogue: D[i][j]: j = lane&15, i = 4*(lane>>4)+reg  [measured layout]
  const int cb = n0 + wc*64 + l16;
  #pragma unroll
  for (int n=0;n<4;n++){
    const int col = cb + n*16;
    const float bv = bias[col];
    #pragma unroll
    for (int m=0;m<4;m++){
      const int rbase = m0 + wr*64 + m*16 + g16*4;
      #pragma unroll
      for (int r=0;r<4;r++){
        float v = acc[m][n][r] + bv;
        const size_t row = (size_t)(rbase + r);
        if constexpr (OMODE==0){
          ((float*)C)[row*N + col] = v;
        } else if constexpr (OMODE==1){
          ((bf16*)C)[row*N + col] = f2b(v * oscale);
        } else if constexpr (OMODE==2){
          v = v / (1.f + __expf(-v));               // swish
          ((bf16*)C)[row*N + col] = f2b(v);
        } else {                                    // V transposed: [b*1024+col][2048]
          const size_t bq = row >> 11, s = row & 2047;
          ((bf16*)C)[(bq*1024 + (size_t)col)*2048 + s] = f2b(v);
        }
      }
    }
  }
}

// ---------------- flash attention (swapped QK^T, lane-local softmax) -------
// grid 1024 linear blocks, XCD-aware: all 16 q-tiles of one (b,h) on one XCD.
// 4 waves/block; wave owns 32 q-rows (2 groups of 16). KV tile = 64.
// Q pre-scaled by 0.125*log2e -> softmax in exp2 domain.
// S^T = mfma_16x16x32(A=K, B=Q): D col=l16=q, row=4*g16+r=kv.
// Common path has ZERO cross-lane ops: per-lane partial l_, defer-max with
// per-lane bound check (__all vote); full cross-lane max only on trigger.
__global__ __launch_bounds__(256) void attn_kernel(
    const bf16* __restrict__ Q, const bf16* __restrict__ Km,
    const bf16* __restrict__ Vt, const int* __restrict__ msk,
    bf16* __restrict__ O)
{
  const int tid = threadIdx.x;
  const int w = tid>>6, lane = tid&63;
  const int g16 = lane>>4, l16 = lane&15;
  const int lin = blockIdx.x;                 // 0..1023
  const int xcd = lin & 7, idx = lin >> 3;    // assume XCD = blockIdx % 8
  const int bh  = xcd*8 + (idx >> 4);         // 8 (b,h) groups per XCD
  const int qt  = idx & 15;
  const int b = bh >> 4, h = bh & 15;
  const int q0 = qt*128 + w*32;

  const bf16* Kb = Km + (size_t)b*2048*1024 + h*64;
  const bf16* Vb = Vt + (size_t)(b*16 + h)*64*2048;
  const int*  mb = msk + b*2048;

  // Q fragments (B-operand): col=q=l16, k=d=g16*8+e (+32)
  bf16x8 qf[2][2];
  #pragma unroll
  for (int qg=0;qg<2;qg++){
    const bf16* qp = Q + (size_t)(b*2048 + q0 + qg*16 + l16)*1024 + h*64 + g16*8;
    qf[qg][0] = *(const bf16x8*)qp;
    qf[qg][1] = *(const bf16x8*)(qp + 32);
  }

  float m_[2] = {-3e38f, -3e38f};
  float l_[2] = {0.f, 0.f};                   // per-lane partials (16 kv each)
  const f32x4 fz = {0.f,0.f,0.f,0.f};
  f32x4 xa[2][4];
  #pragma unroll
  for (int qg=0;qg<2;qg++)
    #pragma unroll
    for (int jd=0;jd<4;jd++) xa[qg][jd] = fz;

  bf16x8 kA[4][2], kB[4][2];

  auto loadK = [&](int kv0, bf16x8 (&kk)[4][2]){
    #pragma unroll
    for (int t=0;t<4;t++){
      const bf16* kp = Kb + (size_t)(kv0 + t*16 + l16)*1024 + g16*8;
      kk[t][0] = *(const bf16x8*)kp;
      kk[t][1] = *(const bf16x8*)(kp + 32);
    }
  };

  auto compute = [&](int kv0, bf16x8 (&kk)[4][2]){
    // V + mask loads issued first; consumed only after softmax -> overlap
    bf16x4 vv[4][4];
    int4 mm[4];
    #pragma unroll
    for (int t=0;t<4;t++){
      mm[t] = *(const int4*)(mb + kv0 + t*16 + 4*g16);
      #pragma unroll
      for (int jd=0;jd<4;jd++)
        vv[t][jd] = *(const bf16x4*)(Vb + (size_t)(jd*16 + l16)*2048 + kv0 + t*16 + 4*g16);
    }
    f32x4 st[2][4];
    __builtin_amdgcn_s_setprio(1);
    #pragma unroll
    for (int t=0;t<4;t++){
      #pragma unroll
      for (int qg=0;qg<2;qg++){
        f32x4 a = fz;
        a = __builtin_amdgcn_mfma_f32_16x16x32_bf16(kk[t][0], qf[qg][0], a, 0,0,0);
        a = __builtin_amdgcn_mfma_f32_16x16x32_bf16(kk[t][1], qf[qg][1], a, 0,0,0);
        st[qg][t] = a;
      }
    }
    __builtin_amdgcn_s_setprio(0);
    bf16x4 pq[2][4];
    #pragma unroll
    for (int qg=0;qg<2;qg++){
      // mask in place
      #pragma unroll
      for (int t=0;t<4;t++){
        st[qg][t][0] = (mm[t].x==0) ? -1.5e10f : st[qg][t][0];
        st[qg][t][1] = (mm[t].y==0) ? -1.5e10f : st[qg][t][1];
        st[qg][t][2] = (mm[t].z==0) ? -1.5e10f : st[qg][t][2];
        st[qg][t][3] = (mm[t].w==0) ? -1.5e10f : st[qg][t][3];
      }
      // per-lane max, explicit tree (depth 4)
      float a0 = fmaxf(st[qg][0][0], st[qg][0][1]);
      float a1 = fmaxf(st[qg][0][2], st[qg][0][3]);
      float a2 = fmaxf(st[qg][1][0], st[qg][1][1]);
      float a3 = fmaxf(st[qg][1][2], st[qg][1][3]);
      float a4 = fmaxf(st[qg][2][0], st[qg][2][1]);
      float a5 = fmaxf(st[qg][2][2], st[qg][2][3]);
      float a6 = fmaxf(st[qg][3][0], st[qg][3][1]);
      float a7 = fmaxf(st[qg][3][2], st[qg][3][3]);
      float tm = fmaxf(fmaxf(fmaxf(a0,a1), fmaxf(a2,a3)),
                       fmaxf(fmaxf(a4,a5), fmaxf(a6,a7)));
      // defer-max: only a wave-uniform vote on the common path
      if (!__all(tm <= m_[qg] + 8.f)){
        float fm = tm;                         // full per-q cross-lane max
        fm = fmaxf(fm, __shfl_xor(fm, 16, 64));
        fm = fmaxf(fm, __shfl_xor(fm, 32, 64));
        const float mn = fmaxf(m_[qg], fm);
        const float sc = ex2(m_[qg] - mn);
        l_[qg] *= sc;
        #pragma unroll
        for (int jd=0;jd<4;jd++) xa[qg][jd] *= sc;
        m_[qg] = mn;
      }
      // exp2 + pack; per-lane partial sum (pairwise tree), NO cross-lane here
      float rs0 = 0.f, rs1 = 0.f;
      #pragma unroll
      for (int t=0;t<4;t++){
        const float p0 = ex2(st[qg][t][0] - m_[qg]);
        const float p1 = ex2(st[qg][t][1] - m_[qg]);
        const float p2 = ex2(st[qg][t][2] - m_[qg]);
        const float p3 = ex2(st[qg][t][3] - m_[qg]);
        pq[qg][t][0] = (bf16)p0;
        pq[qg][t][1] = (bf16)p1;
        pq[qg][t][2] = (bf16)p2;
        pq[qg][t][3] = (bf16)p3;
        rs0 += p0 + p1;
        rs1 += p2 + p3;
      }
      l_[qg] += rs0 + rs1;
    }
    __builtin_amdgcn_s_setprio(1);
    #pragma unroll
    for (int t=0;t<4;t++){
      #pragma unroll
      for (int jd=0;jd<4;jd++){
        xa[0][jd] = mfma16bf(vv[t][jd], pq[0][t], xa[0][jd]);
        xa[1][jd] = mfma16bf(vv[t][jd], pq[1][t], xa[1][jd]);
      }
    }
    __builtin_amdgcn_s_setprio(0);
  };

  loadK(0, kA);
  for (int kv0=0; kv0<2048; kv0+=128){
    loadK(kv0+64, kB);                         // prefetch tile t+1
    compute(kv0, kA);
    if (kv0+128 < 2048) loadK(kv0+128, kA);    // prefetch tile t+2
    compute(kv0+64, kB);
  }

  // write O: lane holds q=l16 (per group), d = jd*16 + 4*g16 + r
  #pragma unroll
  for (int qg=0;qg<2;qg++){
    float lt = l_[qg];                          // final cross-lane sum (once)
    lt += __shfl_xor(lt, 16, 64);
    lt += __shfl_xor(lt, 32, 64);
    const float rl = 1.f / lt;
    const size_t row = (size_t)(b*2048 + q0 + qg*16 + l16);
    #pragma unroll
    for (int jd=0;jd<4;jd++){
      bf16x4 ov = { f2b(xa[qg][jd][0]*rl), f2b(xa[qg][jd][1]*rl),
                    f2b(xa[qg][jd][2]*rl), f2b(xa[qg][jd][3]*rl) };
      *(bf16x4*)(O + row*1024 + h*64 + jd*16 + 4*g16) = ov;
    }
  }
}

// ---------------- residual + layernorm (row = 1024) ----------------
__global__ __launch_bounds__(256) void addln_kernel(
    const float* __restrict__ X, const float* __restrict__ R,
    const float* __restrict__ g, const float* __restrict__ be,
    float* __restrict__ of, bf16* __restrict__ ob)
{
  const int row = blockIdx.x, tid = threadIdx.x;
  const float4 vx = ((const float4*)(X + (size_t)row*1024))[tid];
  const float4 vr = ((const float4*)(R + (size_t)row*1024))[tid];
  const float a0 = vx.x+vr.x, a1 = vx.y+vr.y, a2 = vx.z+vr.z, a3 = vx.w+vr.w;
  float s = a0+a1+a2+a3;
  float q = a0*a0 + a1*a1 + a2*a2 + a3*a3;
  #pragma unroll
  for (int off=1; off<64; off<<=1){
    s += __shfl_xor(s, off, 64);
    q += __shfl_xor(q, off, 64);
  }
  __shared__ float sb[8];
  if ((tid&63)==0){ sb[tid>>6] = s; sb[4+(tid>>6)] = q; }
  __syncthreads();
  s = sb[0]+sb[1]+sb[2]+sb[3];
  q = sb[4]+sb[5]+sb[6]+sb[7];
  const float mu = s*(1.f/1024.f);
  const float rs = rsqrtf(q*(1.f/1024.f) - mu*mu + 1e-5f);
  const float4 gg = ((const float4*)g)[tid];
  const float4 bb = ((const float4*)be)[tid];
  const float o0 = (a0-mu)*rs*gg.x + bb.x;
  const float o1 = (a1-mu)*rs*gg.y + bb.y;
  const float o2 = (a2-mu)*rs*gg.z + bb.z;
  const float o3 = (a3-mu)*rs*gg.w + bb.w;
  float4 o; o.x=o0; o.y=o1; o.z=o2; o.w=o3;
  ((float4*)(of + (size_t)row*1024))[tid] = o;
  if (ob){
    bf16x4 u = { f2b(o0), f2b(o1), f2b(o2), f2b(o3) };
    *(bf16x4*)(ob + (size_t)row*1024 + tid*4) = u;
  }
}

// ---------------- launch ----------------
extern "C" void kernel_launch(void* const* d_in, const int* in_sizes, int n_in,
                              void* d_out, int out_size, void* d_ws, size_t ws_size,
                              hipStream_t stream)
{
  const float* src  = (const float*)d_in[0];
  const int*   mask = (const int*)  d_in[1];
  const float* Wq = (const float*)d_in[2];  const float* bq = (const float*)d_in[3];
  const float* Wk = (const float*)d_in[4];  const float* bk = (const float*)d_in[5];
  const float* Wv = (const float*)d_in[6];  const float* bv = (const float*)d_in[7];
  const float* Wo = (const float*)d_in[8];  const float* bo = (const float*)d_in[9];
  const float* W1 = (const float*)d_in[10]; const float* b1 = (const float*)d_in[11];
  const float* W2 = (const float*)d_in[12]; const float* b2 = (const float*)d_in[13];
  const float* g1 = (const float*)d_in[14]; const float* be1 = (const float*)d_in[15];
  const float* g2 = (const float*)d_in[16]; const float* be2 = (const float*)d_in[17];

  char* ws = (char*)d_ws;
  const size_t MB = 1u<<20;
  bf16* srcb = (bf16*)(ws + 0*MB);     // 16 MB  [dead after QKV gemms]
  bf16* Wqt  = (bf16*)(ws + 16*MB);    // 2 MB
  bf16* Wkt  = (bf16*)(ws + 18*MB);
  bf16* Wvt  = (bf16*)(ws + 20*MB);
  bf16* Wot  = (bf16*)(ws + 22*MB);
  bf16* W1t  = (bf16*)(ws + 24*MB);    // 8 MB
  bf16* W2t  = (bf16*)(ws + 32*MB);    // 8 MB
  bf16* Qb   = (bf16*)(ws + 40*MB);    // 16 MB [dead after attn]
  bf16* Kb   = (bf16*)(ws + 56*MB);    // 16 MB [dead after attn]
  bf16* Vtb  = (bf16*)(ws + 72*MB);    // 16 MB [dead after attn]
  bf16* AO   = (bf16*)(ws + 88*MB);    // 16 MB [dead after O-proj]
  float* X1  = (float*)(ws + 40*MB);   // 32 MB over Qb+Kb
  float* S1F = (float*)(ws + 72*MB);   // 32 MB over Vtb+AO
  bf16*  S1B = (bf16*)(ws + 0*MB);     // 16 MB over srcb
  bf16*  H1  = (bf16*)(ws + 104*MB);   // 64 MB
  float* F2  = (float*)(ws + 40*MB);   // 32 MB over X1 (dead after LN1)

  const float QSC = 0.18033688011112042f;   // 0.125 * log2(e)

  // casts + weight transposes
  castb_kernel<<<8192, 256, 0, stream>>>(src, srcb, 8192*1024/4);
  transcast_kernel<<<dim3(32,32),  dim3(32,8), 0, stream>>>(Wq, Wqt, 1024, 1024);
  transcast_kernel<<<dim3(32,32),  dim3(32,8), 0, stream>>>(Wk, Wkt, 1024, 1024);
  transcast_kernel<<<dim3(32,32),  dim3(32,8), 0, stream>>>(Wv, Wvt, 1024, 1024);
  transcast_kernel<<<dim3(32,32),  dim3(32,8), 0, stream>>>(Wo, Wot, 1024, 1024);
  transcast_kernel<<<dim3(128,32), dim3(32,8), 0, stream>>>(W1, W1t, 1024, 4096);
  transcast_kernel<<<dim3(32,128), dim3(32,8), 0, stream>>>(W2, W2t, 4096, 1024);

  // QKV projections (Q pre-scaled into exp2 softmax domain)
  gemm_bt_kernel<1><<<dim3(8,64),  256, 0, stream>>>(srcb, Wqt, bq, Qb,  8192, 1024, 1024, QSC);
  gemm_bt_kernel<1><<<dim3(8,64),  256, 0, stream>>>(srcb, Wkt, bk, Kb,  8192, 1024, 1024, 1.f);
  gemm_bt_kernel<3><<<dim3(8,64),  256, 0, stream>>>(srcb, Wvt, bv, Vtb, 8192, 1024, 1024, 1.f);

  // attention (1024 linear blocks, XCD-aware (b,h) clustering)
  attn_kernel<<<1024, 256, 0, stream>>>(Qb, Kb, Vtb, mask, AO);

  // output projection + LN1
  gemm_bt_kernel<0><<<dim3(8,64),  256, 0, stream>>>(AO, Wot, bo, X1, 8192, 1024, 1024, 1.f);
  addln_kernel<<<8192, 256, 0, stream>>>(X1, src, g1, be1, S1F, S1B);

  // FFN (swish) + LN2 -> d_out
  gemm_bt_kernel<2><<<dim3(32,64), 256, 0, stream>>>(S1B, W1t, b1, H1, 8192, 4096, 1024, 1.f);
  gemm_bt_kernel<0><<<dim3(8,64),  256, 0, stream>>>(H1,  W2t, b2, F2, 8192, 1024, 4096, 1.f);
  addln_kernel<<<8192, 256, 0, stream>>>(F2, S1F, g2, be2, (float*)d_out, (bf16*)nullptr);
}

// Round 5
// 505.913 us; speedup vs baseline: 1.4411x; 1.4411x over previous
//
#include <hip/hip_runtime.h>
#include <stdint.h>

// EncoderLayer on MI355X (gfx950), bf16 MFMA pipeline.
// B=4, S=2048, HID=1024, HEADS=16, HD=64, PF=4096. M = B*S = 8192.

typedef __bf16 bf16;
typedef __bf16 bf16x4 __attribute__((ext_vector_type(4)));
typedef __bf16 bf16x8 __attribute__((ext_vector_type(8)));
typedef short  s16x4  __attribute__((ext_vector_type(4)));
typedef float  f32x4  __attribute__((ext_vector_type(4)));

__device__ __forceinline__ bf16 f2b(float x){
  uint32_t u = __builtin_bit_cast(uint32_t, x);
  uint32_t r = (u + 0x7FFFu + ((u >> 16) & 1u)) >> 16;   // RNE
  return __builtin_bit_cast(bf16, (uint16_t)r);
}

__device__ __forceinline__ float ex2(float x){
#if __has_builtin(__builtin_amdgcn_exp2f)
  return __builtin_amdgcn_exp2f(x);
#else
  return __exp2f(x);
#endif
}

// 16x16x16 bf16 MFMA (A,B: 4 bf16 / 2 VGPRs each; D: 4 f32)
__device__ __forceinline__ f32x4 mfma16bf(bf16x4 a, bf16x4 b, f32x4 c){
#if __has_builtin(__builtin_amdgcn_mfma_f32_16x16x16_bf16)
  return __builtin_amdgcn_mfma_f32_16x16x16_bf16(a, b, c, 0, 0, 0);
#elif __has_builtin(__builtin_amdgcn_mfma_f32_16x16x16bf16_1k)
  return __builtin_amdgcn_mfma_f32_16x16x16bf16_1k(
      __builtin_bit_cast(s16x4, a), __builtin_bit_cast(s16x4, b), c, 0, 0, 0);
#else
  f32x4 d = c;
  asm volatile("v_mfma_f32_16x16x16_bf16 %0, %1, %2, %0"
               : "+v"(d)
               : "v"(__builtin_bit_cast(s16x4, a)), "v"(__builtin_bit_cast(s16x4, b)));
  return d;
#endif
}

// async global->LDS, 16B per lane (LDS dest = wave-uniform base + lane*16)
__device__ __forceinline__ void gload_lds16(const bf16* g, bf16* l){
  __builtin_amdgcn_global_load_lds(
      (const __attribute__((address_space(1))) void*)g,
      (__attribute__((address_space(3))) void*)l, 16, 0, 0);
}

// ---------------- cast f32 -> bf16 (vectorized) ----------------
__global__ __launch_bounds__(256) void castb_kernel(const float* __restrict__ in,
                                                    bf16* __restrict__ out, int n4){
  const int i = blockIdx.x*256 + threadIdx.x;
  if (i >= n4) return;
  const float4 v = ((const float4*)in)[i];
  bf16x4 u = { f2b(v.x), f2b(v.y), f2b(v.z), f2b(v.w) };
  *(bf16x4*)(out + (size_t)i*4) = u;
}

// ---------------- transpose+cast W[K][N] f32 -> Wt[N][K] bf16 ----------------
__global__ void transcast_kernel(const float* __restrict__ W, bf16* __restrict__ Wt,
                                 int K, int N){
  __shared__ float t[32][33];
  const int x = threadIdx.x, y = threadIdx.y;           // (32,8)
  const int n0 = blockIdx.x*32, k0 = blockIdx.y*32;
  #pragma unroll
  for (int r=0;r<4;r++) t[y+8*r][x] = W[(size_t)(k0+y+8*r)*N + n0+x];
  __syncthreads();
  #pragma unroll
  for (int r=0;r<4;r++) Wt[(size_t)(n0+y+8*r)*K + k0+x] = f2b(t[x][y+8*r]);
}

// ---------------- GEMM: C = A[M][K] * Bt[N][K]^T + bias ----------------
// 128x128 tile, 4 waves (2x2), wave = 64x64 = 4x4 frags of 16x16x32 MFMA.
// Reg-staged LDS with next-K-tile register prefetch (known-good 834 TF).
// LDS [128][32] bf16, 16B-slot XOR swizzle slot^=(row>>1)&3.
// OMODE: 0=f32, 1=bf16 (scaled by oscale), 2=bf16+swish,
//        3=bf16 V-transposed [b*1024+col][2048]
template<int OMODE>
__global__ __launch_bounds__(256) void gemm_bt_kernel(
    const bf16* __restrict__ A, const bf16* __restrict__ Bt,
    const float* __restrict__ bias, void* __restrict__ C,
    int M, int N, int K, float oscale)
{
  __shared__ bf16 As[128*32];
  __shared__ bf16 Bs[128*32];
  const int tid = threadIdx.x;
  const int w = tid >> 6, lane = tid & 63;
  const int wr = w >> 1, wc = w & 1;
  const int g16 = lane >> 4, l16 = lane & 15;
  const int m0 = blockIdx.y*128, n0 = blockIdx.x*128;

  const int ar = tid >> 2, asl = tid & 3;
  const bf16* gA = A  + (size_t)(m0+ar)*K + asl*8;
  const bf16* gB = Bt + (size_t)(n0+ar)*K + asl*8;
  const int sw0 = (ar>>1)&3;
  const int la = ar*32      + ((asl ^ sw0)<<3);
  const int lb = (ar+64)*32 + ((asl ^ sw0)<<3);

  f32x4 acc[4][4];
  const f32x4 fz = {0.f,0.f,0.f,0.f};
  #pragma unroll
  for (int m=0;m<4;m++)
    #pragma unroll
    for (int n=0;n<4;n++) acc[m][n] = fz;

  bf16x8 ra0 = *(const bf16x8*)gA;
  bf16x8 ra1 = *(const bf16x8*)(gA + (size_t)64*K);
  bf16x8 rb0 = *(const bf16x8*)gB;
  bf16x8 rb1 = *(const bf16x8*)(gB + (size_t)64*K);

  for (int k0=0; k0<K; k0+=32){
    __syncthreads();
    *(bf16x8*)&As[la] = ra0;
    *(bf16x8*)&As[lb] = ra1;
    *(bf16x8*)&Bs[la] = rb0;
    *(bf16x8*)&Bs[lb] = rb1;
    __syncthreads();
    if (k0 + 32 < K){
      ra0 = *(const bf16x8*)(gA + k0+32);
      ra1 = *(const bf16x8*)(gA + (size_t)64*K + k0+32);
      rb0 = *(const bf16x8*)(gB + k0+32);
      rb1 = *(const bf16x8*)(gB + (size_t)64*K + k0+32);
    }
    bf16x8 af[4], bfv[4];
    #pragma unroll
    for (int m=0;m<4;m++){
      const int r = wr*64 + m*16 + l16;
      af[m] = *(const bf16x8*)&As[r*32 + ((g16 ^ ((r>>1)&3))<<3)];
    }
    #pragma unroll
    for (int n=0;n<4;n++){
      const int r = wc*64 + n*16 + l16;
      bfv[n] = *(const bf16x8*)&Bs[r*32 + ((g16 ^ ((r>>1)&3))<<3)];
    }
    #pragma unroll
    for (int m=0;m<4;m++)
      #pragma unroll
      for (int n=0;n<4;n++)
        acc[m][n] = __builtin_amdgcn_mfma_f32_16x16x32_bf16(af[m], bfv[n], acc[m][n], 0, 0, 0);
  }

  // epilogue: D[i][j]: j = lane&15, i = 4*(lane>>4)+reg  [measured layout]
  const int cb = n0 + wc*64 + l16;
  #pragma unroll
  for (int n=0;n<4;n++){
    const int col = cb + n*16;
    const float bv = bias[col];
    #pragma unroll
    for (int m=0;m<4;m++){
      const int rbase = m0 + wr*64 + m*16 + g16*4;
      #pragma unroll
      for (int r=0;r<4;r++){
        float v = acc[m][n][r] + bv;
        const size_t row = (size_t)(rbase + r);
        if constexpr (OMODE==0){
          ((float*)C)[row*N + col] = v;
        } else if constexpr (OMODE==1){
          ((bf16*)C)[row*N + col] = f2b(v * oscale);
        } else if constexpr (OMODE==2){
          v = v / (1.f + __expf(-v));               // swish
          ((bf16*)C)[row*N + col] = f2b(v);
        } else {                                    // V transposed: [b*1024+col][2048]
          const size_t bq = row >> 11, s = row & 2047;
          ((bf16*)C)[(bq*1024 + (size_t)col)*2048 + s] = f2b(v);
        }
      }
    }
  }
}

// ---------------- flash attention (block-cooperative LDS K/V staging) ------
// grid 1024 linear blocks, XCD-aware: all 16 q-tiles of one (b,h) on one XCD.
// 4 waves/block; wave owns 32 q-rows (2 groups of 16). KV tile = 64.
// K fragment and V fragment are q-independent -> staged ONCE per block in LDS
// (global_load_lds w16, double-buffered, 8-slot XOR swizzle slot^=row&7 as a
// both-sides involution: inverse-swizzled global source + swizzled LDS read).
// One __syncthreads per tile (implicit vmcnt/lgkm drain covers the dbuf).
// Q pre-scaled by 0.125*log2e -> softmax in exp2 domain, lane-local partials.
__global__ __launch_bounds__(256) void attn_kernel(
    const bf16* __restrict__ Q, const bf16* __restrict__ Km,
    const bf16* __restrict__ Vt, const int* __restrict__ msk,
    bf16* __restrict__ O)
{
  __shared__ bf16 Ks[2][64*64];   // [64 kv-rows][128B] per buf (8 KB)
  __shared__ bf16 Vs[2][64*64];   // [64 d-rows ][128B] per buf (8 KB)

  const int tid = threadIdx.x;
  const int w = tid>>6, lane = tid&63;
  const int g16 = lane>>4, l16 = lane&15;
  const int lin = blockIdx.x;                 // 0..1023
  const int xcd = lin & 7, idx = lin >> 3;    // XCD = blockIdx % 8
  const int bh  = xcd*8 + (idx >> 4);         // 8 (b,h) groups per XCD
  const int qt  = idx & 15;
  const int b = bh >> 4, h = bh & 15;
  const int q0 = qt*128 + w*32;

  const bf16* Kb = Km + (size_t)b*2048*1024 + h*64;
  const bf16* Vb = Vt + (size_t)(b*16 + h)*64*2048;
  const int*  mb = msk + b*2048;

  // ---- staging addresses (loop-invariant) ----
  // row within tile r = w*16 + i*8 + (lane>>3), phys 16B-slot p = lane&7,
  // source data slot s = p ^ (r&7) = (lane&7) ^ (lane>>3)  [w*16,i*8 == 0 mod 8]
  const int srow = w*16 + (lane>>3);
  const int sslot = ((lane&7) ^ (lane>>3)) * 8;           // element offset
  const bf16* gK0 = Kb + (size_t)srow*1024 + sslot;       // + kv0*1024 per tile
  const bf16* gK1 = gK0 + (size_t)8*1024;                 // row+8, same slot
  const bf16* gV0 = Vb + (size_t)srow*2048 + sslot;       // + kv0 per tile
  const bf16* gV1 = gV0 + (size_t)8*2048;

  // ---- read offsets (loop-invariant) ----
  const int l7 = l16 & 7;
  // K frags: row = t*16+l16, slot = (4j+g16)^(row&7); element addr = row*64 + slot*8
  const int kOff0 = l16*64 + ((g16     ^ l7) << 3);
  const int kOff1 = l16*64 + (((4+g16) ^ l7) << 3);
  // V frags: row = jd*16+l16, slot = (2t+(g16>>1))^(row&7), +8B half (g16&1)
  // element addr = row*64 + slot*8 + (g16&1)*4
  int vOff[4];   // per t; add jd*16*64 per fragment row group
  #pragma unroll
  for (int t=0;t<4;t++)
    vOff[t] = l16*64 + ((((t<<1) + (g16>>1)) ^ l7) << 3) + ((g16&1)<<2);

  // Q fragments (B-operand): col=q=l16, k=d=g16*8+e (+32)
  bf16x8 qf[2][2];
  #pragma unroll
  for (int qg=0;qg<2;qg++){
    const bf16* qp = Q + (size_t)(b*2048 + q0 + qg*16 + l16)*1024 + h*64 + g16*8;
    qf[qg][0] = *(const bf16x8*)qp;
    qf[qg][1] = *(const bf16x8*)(qp + 32);
  }

  float m_[2] = {-3e38f, -3e38f};
  float l_[2] = {0.f, 0.f};                   // per-lane partials (16 kv each)
  const f32x4 fz = {0.f,0.f,0.f,0.f};
  f32x4 xa[2][4];
  #pragma unroll
  for (int qg=0;qg<2;qg++)
    #pragma unroll
    for (int jd=0;jd<4;jd++) xa[qg][jd] = fz;

  auto stage = [&](int buf, int kv0){
    bf16* kl = &Ks[buf][w*1024];
    bf16* vl = &Vs[buf][w*1024];
    gload_lds16(gK0 + (size_t)kv0*1024, kl);
    gload_lds16(gK1 + (size_t)kv0*1024, kl + 512);
    gload_lds16(gV0 + kv0,              vl);
    gload_lds16(gV1 + kv0,              vl + 512);
  };

  stage(0, 0);
  __syncthreads();                             // drains vmcnt(0) then barrier

  int cur = 0;
  for (int kv0 = 0; kv0 < 2048; kv0 += 64){
    if (kv0 + 64 < 2048) stage(cur^1, kv0+64); // async prefetch next tile
    // mask loads (4 distinct 16B addrs, broadcast within wave)
    int4 mm[4];
    #pragma unroll
    for (int t=0;t<4;t++) mm[t] = *(const int4*)(mb + kv0 + t*16 + 4*g16);

    const bf16* ksb = &Ks[cur][0];
    const bf16* vsb = &Vs[cur][0];
    // K fragments from LDS
    bf16x8 kk[4][2];
    #pragma unroll
    for (int t=0;t<4;t++){
      kk[t][0] = *(const bf16x8*)(ksb + t*1024 + kOff0);
      kk[t][1] = *(const bf16x8*)(ksb + t*1024 + kOff1);
    }
    // QK^T
    f32x4 st[2][4];
    __builtin_amdgcn_s_setprio(1);
    #pragma unroll
    for (int t=0;t<4;t++){
      #pragma unroll
      for (int qg=0;qg<2;qg++){
        f32x4 a = fz;
        a = __builtin_amdgcn_mfma_f32_16x16x32_bf16(kk[t][0], qf[qg][0], a, 0,0,0);
        a = __builtin_amdgcn_mfma_f32_16x16x32_bf16(kk[t][1], qf[qg][1], a, 0,0,0);
        st[qg][t] = a;
      }
    }
    __builtin_amdgcn_s_setprio(0);
    // V fragments from LDS (issued before softmax; consumed after)
    bf16x4 vv[4][4];
    #pragma unroll
    for (int t=0;t<4;t++)
      #pragma unroll
      for (int jd=0;jd<4;jd++)
        vv[t][jd] = *(const bf16x4*)(vsb + jd*1024 + vOff[t]);
    // softmax (lane-local; cross-lane only on defer-max trigger)
    bf16x4 pq[2][4];
    #pragma unroll
    for (int qg=0;qg<2;qg++){
      #pragma unroll
      for (int t=0;t<4;t++){
        st[qg][t][0] = (mm[t].x==0) ? -1.5e10f : st[qg][t][0];
        st[qg][t][1] = (mm[t].y==0) ? -1.5e10f : st[qg][t][1];
        st[qg][t][2] = (mm[t].z==0) ? -1.5e10f : st[qg][t][2];
        st[qg][t][3] = (mm[t].w==0) ? -1.5e10f : st[qg][t][3];
      }
      float a0 = fmaxf(st[qg][0][0], st[qg][0][1]);
      float a1 = fmaxf(st[qg][0][2], st[qg][0][3]);
      float a2 = fmaxf(st[qg][1][0], st[qg][1][1]);
      float a3 = fmaxf(st[qg][1][2], st[qg][1][3]);
      float a4 = fmaxf(st[qg][2][0], st[qg][2][1]);
      float a5 = fmaxf(st[qg][2][2], st[qg][2][3]);
      float a6 = fmaxf(st[qg][3][0], st[qg][3][1]);
      float a7 = fmaxf(st[qg][3][2], st[qg][3][3]);
      float tm = fmaxf(fmaxf(fmaxf(a0,a1), fmaxf(a2,a3)),
                       fmaxf(fmaxf(a4,a5), fmaxf(a6,a7)));
      if (!__all(tm <= m_[qg] + 8.f)){
        float fm = tm;
        fm = fmaxf(fm, __shfl_xor(fm, 16, 64));
        fm = fmaxf(fm, __shfl_xor(fm, 32, 64));
        const float mn = fmaxf(m_[qg], fm);
        const float sc = ex2(m_[qg] - mn);
        l_[qg] *= sc;
        #pragma unroll
        for (int jd=0;jd<4;jd++) xa[qg][jd] *= sc;
        m_[qg] = mn;
      }
      float rs0 = 0.f, rs1 = 0.f;
      #pragma unroll
      for (int t=0;t<4;t++){
        const float p0 = ex2(st[qg][t][0] - m_[qg]);
        const float p1 = ex2(st[qg][t][1] - m_[qg]);
        const float p2 = ex2(st[qg][t][2] - m_[qg]);
        const float p3 = ex2(st[qg][t][3] - m_[qg]);
        pq[qg][t][0] = (bf16)p0;
        pq[qg][t][1] = (bf16)p1;
        pq[qg][t][2] = (bf16)p2;
        pq[qg][t][3] = (bf16)p3;
        rs0 += p0 + p1;
        rs1 += p2 + p3;
      }
      l_[qg] += rs0 + rs1;
    }
    // PV
    __builtin_amdgcn_s_setprio(1);
    #pragma unroll
    for (int t=0;t<4;t++){
      #pragma unroll
      for (int jd=0;jd<4;jd++){
        xa[0][jd] = mfma16bf(vv[t][jd], pq[0][t], xa[0][jd]);
        xa[1][jd] = mfma16bf(vv[t][jd], pq[1][t], xa[1][jd]);
      }
    }
    __builtin_amdgcn_s_setprio(0);
    __syncthreads();                           // reads done + next stage landed
    cur ^= 1;
  }

  // write O: lane holds q=l16 (per group), d = jd*16 + 4*g16 + r
  #pragma unroll
  for (int qg=0;qg<2;qg++){
    float lt = l_[qg];                          // final cross-lane sum (once)
    lt += __shfl_xor(lt, 16, 64);
    lt += __shfl_xor(lt, 32, 64);
    const float rl = 1.f / lt;
    const size_t row = (size_t)(b*2048 + q0 + qg*16 + l16);
    #pragma unroll
    for (int jd=0;jd<4;jd++){
      bf16x4 ov = { f2b(xa[qg][jd][0]*rl), f2b(xa[qg][jd][1]*rl),
                    f2b(xa[qg][jd][2]*rl), f2b(xa[qg][jd][3]*rl) };
      *(bf16x4*)(O + row*1024 + h*64 + jd*16 + 4*g16) = ov;
    }
  }
}

// ---------------- residual + layernorm (row = 1024) ----------------
__global__ __launch_bounds__(256) void addln_kernel(
    const float* __restrict__ X, const float* __restrict__ R,
    const float* __restrict__ g, const float* __restrict__ be,
    float* __restrict__ of, bf16* __restrict__ ob)
{
  const int row = blockIdx.x, tid = threadIdx.x;
  const float4 vx = ((const float4*)(X + (size_t)row*1024))[tid];
  const float4 vr = ((const float4*)(R + (size_t)row*1024))[tid];
  const float a0 = vx.x+vr.x, a1 = vx.y+vr.y, a2 = vx.z+vr.z, a3 = vx.w+vr.w;
  float s = a0+a1+a2+a3;
  float q = a0*a0 + a1*a1 + a2*a2 + a3*a3;
  #pragma unroll
  for (int off=1; off<64; off<<=1){
    s += __shfl_xor(s, off, 64);
    q += __shfl_xor(q, off, 64);
  }
  __shared__ float sb[8];
  if ((tid&63)==0){ sb[tid>>6] = s; sb[4+(tid>>6)] = q; }
  __syncthreads();
  s = sb[0]+sb[1]+sb[2]+sb[3];
  q = sb[4]+sb[5]+sb[6]+sb[7];
  const float mu = s*(1.f/1024.f);
  const float rs = rsqrtf(q*(1.f/1024.f) - mu*mu + 1e-5f);
  const float4 gg = ((const float4*)g)[tid];
  const float4 bb = ((const float4*)be)[tid];
  const float o0 = (a0-mu)*rs*gg.x + bb.x;
  const float o1 = (a1-mu)*rs*gg.y + bb.y;
  const float o2 = (a2-mu)*rs*gg.z + bb.z;
  const float o3 = (a3-mu)*rs*gg.w + bb.w;
  float4 o; o.x=o0; o.y=o1; o.z=o2; o.w=o3;
  ((float4*)(of + (size_t)row*1024))[tid] = o;
  if (ob){
    bf16x4 u = { f2b(o0), f2b(o1), f2b(o2), f2b(o3) };
    *(bf16x4*)(ob + (size_t)row*1024 + tid*4) = u;
  }
}

// ---------------- launch ----------------
extern "C" void kernel_launch(void* const* d_in, const int* in_sizes, int n_in,
                              void* d_out, int out_size, void* d_ws, size_t ws_size,
                              hipStream_t stream)
{
  const float* src  = (const float*)d_in[0];
  const int*   mask = (const int*)  d_in[1];
  const float* Wq = (const float*)d_in[2];  const float* bq = (const float*)d_in[3];
  const float* Wk = (const float*)d_in[4];  const float* bk = (const float*)d_in[5];
  const float* Wv = (const float*)d_in[6];  const float* bv = (const float*)d_in[7];
  const float* Wo = (const float*)d_in[8];  const float* bo = (const float*)d_in[9];
  const float* W1 = (const float*)d_in[10]; const float* b1 = (const float*)d_in[11];
  const float* W2 = (const float*)d_in[12]; const float* b2 = (const float*)d_in[13];
  const float* g1 = (const float*)d_in[14]; const float* be1 = (const float*)d_in[15];
  const float* g2 = (const float*)d_in[16]; const float* be2 = (const float*)d_in[17];

  char* ws = (char*)d_ws;
  const size_t MB = 1u<<20;
  bf16* srcb = (bf16*)(ws + 0*MB);     // 16 MB  [dead after QKV gemms]
  bf16* Wqt  = (bf16*)(ws + 16*MB);    // 2 MB
  bf16* Wkt  = (bf16*)(ws + 18*MB);
  bf16* Wvt  = (bf16*)(ws + 20*MB);
  bf16* Wot  = (bf16*)(ws + 22*MB);
  bf16* W1t  = (bf16*)(ws + 24*MB);    // 8 MB
  bf16* W2t  = (bf16*)(ws + 32*MB);    // 8 MB
  bf16* Qb   = (bf16*)(ws + 40*MB);    // 16 MB [dead after attn]
  bf16* Kb   = (bf16*)(ws + 56*MB);    // 16 MB [dead after attn]
  bf16* Vtb  = (bf16*)(ws + 72*MB);    // 16 MB [dead after attn]
  bf16* AO   = (bf16*)(ws + 88*MB);    // 16 MB [dead after O-proj]
  float* X1  = (float*)(ws + 40*MB);   // 32 MB over Qb+Kb
  float* S1F = (float*)(ws + 72*MB);   // 32 MB over Vtb+AO
  bf16*  S1B = (bf16*)(ws + 0*MB);     // 16 MB over srcb
  bf16*  H1  = (bf16*)(ws + 104*MB);   // 64 MB
  float* F2  = (float*)(ws + 40*MB);   // 32 MB over X1 (dead after LN1)

  const float QSC = 0.18033688011112042f;   // 0.125 * log2(e)

  // casts + weight transposes
  castb_kernel<<<8192, 256, 0, stream>>>(src, srcb, 8192*1024/4);
  transcast_kernel<<<dim3(32,32),  dim3(32,8), 0, stream>>>(Wq, Wqt, 1024, 1024);
  transcast_kernel<<<dim3(32,32),  dim3(32,8), 0, stream>>>(Wk, Wkt, 1024, 1024);
  transcast_kernel<<<dim3(32,32),  dim3(32,8), 0, stream>>>(Wv, Wvt, 1024, 1024);
  transcast_kernel<<<dim3(32,32),  dim3(32,8), 0, stream>>>(Wo, Wot, 1024, 1024);
  transcast_kernel<<<dim3(128,32), dim3(32,8), 0, stream>>>(W1, W1t, 1024, 4096);
  transcast_kernel<<<dim3(32,128), dim3(32,8), 0, stream>>>(W2, W2t, 4096, 1024);

  // QKV projections (Q pre-scaled into exp2 softmax domain)
  gemm_bt_kernel<1><<<dim3(8,64),  256, 0, stream>>>(srcb, Wqt, bq, Qb,  8192, 1024, 1024, QSC);
  gemm_bt_kernel<1><<<dim3(8,64),  256, 0, stream>>>(srcb, Wkt, bk, Kb,  8192, 1024, 1024, 1.f);
  gemm_bt_kernel<3><<<dim3(8,64),  256, 0, stream>>>(srcb, Wvt, bv, Vtb, 8192, 1024, 1024, 1.f);

  // attention (1024 linear blocks, XCD-aware (b,h) clustering)
  attn_kernel<<<1024, 256, 0, stream>>>(Qb, Kb, Vtb, mask, AO);

  // output projection + LN1
  gemm_bt_kernel<0><<<dim3(8,64),  256, 0, stream>>>(AO, Wot, bo, X1, 8192, 1024, 1024, 1.f);
  addln_kernel<<<8192, 256, 0, stream>>>(X1, src, g1, be1, S1F, S1B);

  // FFN (swish) + LN2 -> d_out
  gemm_bt_kernel<2><<<dim3(32,64), 256, 0, stream>>>(S1B, W1t, b1, H1, 8192, 4096, 1024, 1.f);
  gemm_bt_kernel<0><<<dim3(8,64),  256, 0, stream>>>(H1,  W2t, b2, F2, 8192, 1024, 4096, 1.f);
  addln_kernel<<<8192, 256, 0, stream>>>(F2, S1F, g2, be2, (float*)d_out, (bf16*)nullptr);
}

// Round 6
// 493.151 us; speedup vs baseline: 1.4784x; 1.0259x over previous
//
#include <hip/hip_runtime.h>
#include <stdint.h>

// EncoderLayer on MI355X (gfx950), bf16 MFMA pipeline.
// B=4, S=2048, HID=1024, HEADS=16, HD=64, PF=4096. M = B*S = 8192.

typedef __bf16 bf16;
typedef __bf16 bf16x4 __attribute__((ext_vector_type(4)));
typedef __bf16 bf16x8 __attribute__((ext_vector_type(8)));
typedef short  s16x4  __attribute__((ext_vector_type(4)));
typedef float  f32x4  __attribute__((ext_vector_type(4)));

__device__ __forceinline__ bf16 f2b(float x){
  uint32_t u = __builtin_bit_cast(uint32_t, x);
  uint32_t r = (u + 0x7FFFu + ((u >> 16) & 1u)) >> 16;   // RNE
  return __builtin_bit_cast(bf16, (uint16_t)r);
}

__device__ __forceinline__ float ex2(float x){
#if __has_builtin(__builtin_amdgcn_exp2f)
  return __builtin_amdgcn_exp2f(x);
#else
  return __exp2f(x);
#endif
}

// 16x16x16 bf16 MFMA (A,B: 4 bf16 / 2 VGPRs each; D: 4 f32)
__device__ __forceinline__ f32x4 mfma16bf(bf16x4 a, bf16x4 b, f32x4 c){
#if __has_builtin(__builtin_amdgcn_mfma_f32_16x16x16_bf16)
  return __builtin_amdgcn_mfma_f32_16x16x16_bf16(a, b, c, 0, 0, 0);
#elif __has_builtin(__builtin_amdgcn_mfma_f32_16x16x16bf16_1k)
  return __builtin_amdgcn_mfma_f32_16x16x16bf16_1k(
      __builtin_bit_cast(s16x4, a), __builtin_bit_cast(s16x4, b), c, 0, 0, 0);
#else
  f32x4 d = c;
  asm volatile("v_mfma_f32_16x16x16_bf16 %0, %1, %2, %0"
               : "+v"(d)
               : "v"(__builtin_bit_cast(s16x4, a)), "v"(__builtin_bit_cast(s16x4, b)));
  return d;
#endif
}

// async global->LDS, 16B per lane (LDS dest = wave-uniform base + lane*16,
// global source is per-lane)
__device__ __forceinline__ void gload_lds16(const void* g, void* l){
  __builtin_amdgcn_global_load_lds(
      (const __attribute__((address_space(1))) void*)g,
      (__attribute__((address_space(3))) void*)l, 16, 0, 0);
}

// ---------------- prep: src cast + all 6 weight transposes, one launch ------
// blocks [0,8192): castb of src (f32->bf16, float4/lane)
// blocks [8192,20480): transcast W[K][N] f32 -> Wt[N][K] bf16, 32x32 tiles
__global__ __launch_bounds__(256) void prep_kernel(
    const float* __restrict__ src, bf16* __restrict__ srcb,
    const float* __restrict__ Wq, const float* __restrict__ Wk,
    const float* __restrict__ Wv, const float* __restrict__ Wo,
    const float* __restrict__ W1, const float* __restrict__ W2,
    bf16* __restrict__ Wqkvt, bf16* __restrict__ Wot,
    bf16* __restrict__ W1t,  bf16* __restrict__ W2t)
{
  __shared__ float t[32][33];
  const int bb = blockIdx.x, tid = threadIdx.x;
  if (bb < 8192){
    const int i = bb*256 + tid;                     // n4 = 2097152 exactly
    const float4 v = ((const float4*)src)[i];
    bf16x4 u = { f2b(v.x), f2b(v.y), f2b(v.z), f2b(v.w) };
    *(bf16x4*)(srcb + (size_t)i*4) = u;
    return;
  }
  const int idx = bb - 8192;
  const float* W; bf16* Wt; int K, N, bx, by;
  if (idx < 3072){                                  // Wq/Wk/Wv -> Wqkvt slices
    const int r = idx >> 10, j = idx & 1023;
    W = (r==0)?Wq:(r==1)?Wk:Wv; Wt = Wqkvt + (size_t)r*1024*1024;
    K = 1024; N = 1024; bx = j & 31; by = j >> 5;
  } else if (idx < 4096){
    const int j = idx - 3072;
    W = Wo; Wt = Wot; K = 1024; N = 1024; bx = j & 31; by = j >> 5;
  } else if (idx < 8192){
    const int j = idx - 4096;
    W = W1; Wt = W1t; K = 1024; N = 4096; bx = j & 127; by = j >> 7;
  } else {
    const int j = idx - 8192;
    W = W2; Wt = W2t; K = 4096; N = 1024; bx = j & 31; by = j >> 5;
  }
  const int x = tid & 31, y = tid >> 5;             // (32,8)
  const int n0 = bx*32, k0 = by*32;
  #pragma unroll
  for (int r=0;r<4;r++) t[y+8*r][x] = W[(size_t)(k0+y+8*r)*N + n0+x];
  __syncthreads();
  #pragma unroll
  for (int r=0;r<4;r++) Wt[(size_t)(n0+y+8*r)*K + k0+x] = f2b(t[x][y+8*r]);
}

// ---------------- GEMM: C = A[M][K] * Bt[N][K]^T + bias ----------------
// 128x128 tile, 4 waves (2x2), wave = 64x64 = 4x4 frags of 16x16x32 MFMA.
// Reg-staged LDS with next-K-tile register prefetch (known-good ~858 TF).
// LDS [128][32] bf16, 16B-slot XOR swizzle slot^=(row>>1)&3.
// OMODE: 0=f32, 1=bf16 (scaled by oscale), 2=bf16+swish,
//        3=bf16 V-transposed [b*1024+col][2048],
//        4=fused QKV: col<1024 -> C=Q (scaled), <2048 -> C2=K, else C3=V^T
template<int OMODE>
__global__ __launch_bounds__(256) void gemm_bt_kernel(
    const bf16* __restrict__ A, const bf16* __restrict__ Bt,
    const float* __restrict__ bias, void* __restrict__ C,
    int M, int N, int K, float oscale,
    const float* __restrict__ bias2, const float* __restrict__ bias3,
    void* __restrict__ C2, void* __restrict__ C3)
{
  __shared__ bf16 As[128*32];
  __shared__ bf16 Bs[128*32];
  const int tid = threadIdx.x;
  const int w = tid >> 6, lane = tid & 63;
  const int wr = w >> 1, wc = w & 1;
  const int g16 = lane >> 4, l16 = lane & 15;
  const int m0 = blockIdx.y*128, n0 = blockIdx.x*128;

  const int ar = tid >> 2, asl = tid & 3;
  const bf16* gA = A  + (size_t)(m0+ar)*K + asl*8;
  const bf16* gB = Bt + (size_t)(n0+ar)*K + asl*8;
  const int sw0 = (ar>>1)&3;
  const int la = ar*32      + ((asl ^ sw0)<<3);
  const int lb = (ar+64)*32 + ((asl ^ sw0)<<3);

  f32x4 acc[4][4];
  const f32x4 fz = {0.f,0.f,0.f,0.f};
  #pragma unroll
  for (int m=0;m<4;m++)
    #pragma unroll
    for (int n=0;n<4;n++) acc[m][n] = fz;

  bf16x8 ra0 = *(const bf16x8*)gA;
  bf16x8 ra1 = *(const bf16x8*)(gA + (size_t)64*K);
  bf16x8 rb0 = *(const bf16x8*)gB;
  bf16x8 rb1 = *(const bf16x8*)(gB + (size_t)64*K);

  for (int k0=0; k0<K; k0+=32){
    __syncthreads();
    *(bf16x8*)&As[la] = ra0;
    *(bf16x8*)&As[lb] = ra1;
    *(bf16x8*)&Bs[la] = rb0;
    *(bf16x8*)&Bs[lb] = rb1;
    __syncthreads();
    if (k0 + 32 < K){
      ra0 = *(const bf16x8*)(gA + k0+32);
      ra1 = *(const bf16x8*)(gA + (size_t)64*K + k0+32);
      rb0 = *(const bf16x8*)(gB + k0+32);
      rb1 = *(const bf16x8*)(gB + (size_t)64*K + k0+32);
    }
    bf16x8 af[4], bfv[4];
    #pragma unroll
    for (int m=0;m<4;m++){
      const int r = wr*64 + m*16 + l16;
      af[m] = *(const bf16x8*)&As[r*32 + ((g16 ^ ((r>>1)&3))<<3)];
    }
    #pragma unroll
    for (int n=0;n<4;n++){
      const int r = wc*64 + n*16 + l16;
      bfv[n] = *(const bf16x8*)&Bs[r*32 + ((g16 ^ ((r>>1)&3))<<3)];
    }
    #pragma unroll
    for (int m=0;m<4;m++)
      #pragma unroll
      for (int n=0;n<4;n++)
        acc[m][n] = __builtin_amdgcn_mfma_f32_16x16x32_bf16(af[m], bfv[n], acc[m][n], 0, 0, 0);
  }

  // epilogue: D[i][j]: j = lane&15, i = 4*(lane>>4)+reg  [measured layout]
  const int cb = n0 + wc*64 + l16;
  if constexpr (OMODE==4){
    const int region = n0 >> 10;                    // block-uniform
    const float* bs = (region==0)? bias : (region==1)? bias2 : bias3;
    const int colbase = region << 10;
    #pragma unroll
    for (int n=0;n<4;n++){
      const int cl = cb + n*16 - colbase;
      const float bv = bs[cl];
      #pragma unroll
      for (int m=0;m<4;m++){
        const int rbase = m0 + wr*64 + m*16 + g16*4;
        #pragma unroll
        for (int r=0;r<4;r++){
          const float v = acc[m][n][r] + bv;
          const size_t row = (size_t)(rbase + r);
          if (region==0)      ((bf16*)C )[row*1024 + cl] = f2b(v * oscale);
          else if (region==1) ((bf16*)C2)[row*1024 + cl] = f2b(v);
          else {
            const size_t bq = row >> 11, s = row & 2047;
            ((bf16*)C3)[(bq*1024 + (size_t)cl)*2048 + s] = f2b(v);
          }
        }
      }
    }
  } else {
    #pragma unroll
    for (int n=0;n<4;n++){
      const int col = cb + n*16;
      const float bv = bias[col];
      #pragma unroll
      for (int m=0;m<4;m++){
        const int rbase = m0 + wr*64 + m*16 + g16*4;
        #pragma unroll
        for (int r=0;r<4;r++){
          float v = acc[m][n][r] + bv;
          const size_t row = (size_t)(rbase + r);
          if constexpr (OMODE==0){
            ((float*)C)[row*N + col] = v;
          } else if constexpr (OMODE==1){
            ((bf16*)C)[row*N + col] = f2b(v * oscale);
          } else if constexpr (OMODE==2){
            v = v / (1.f + __expf(-v));             // swish
            ((bf16*)C)[row*N + col] = f2b(v);
          } else {
            const size_t bq = row >> 11, s = row & 2047;
            ((bf16*)C)[(bq*1024 + (size_t)col)*2048 + s] = f2b(v);
          }
        }
      }
    }
  }
}

// ---------------- flash attention (depth-2 pipelined LDS K/V staging) ------
// grid 1024 linear blocks, XCD-aware (b,h) clustering. 4 waves/block,
// wave owns 32 q-rows (2x16). KV tile = 64, THREE LDS buffers, stage(t+2)
// in flight across raw s_barrier with counted s_waitcnt vmcnt(4) (T4).
// Mask row staged to LDS once in prologue -> zero in-loop global loads
// besides staging, so vmcnt counts exactly the staging pipeline.
// Q pre-scaled by 0.125*log2e -> softmax in exp2 domain, lane-local partials.
__global__ __launch_bounds__(256) void attn_kernel(
    const bf16* __restrict__ Q, const bf16* __restrict__ Km,
    const bf16* __restrict__ Vt, const int* __restrict__ msk,
    bf16* __restrict__ O)
{
  __shared__ bf16 Ks[3][64*64];   // 8 KB per buf
  __shared__ bf16 Vs[3][64*64];   // 8 KB per buf
  __shared__ int  Mq[2048];       // 8 KB mask row

  const int tid = threadIdx.x;
  const int w = tid>>6, lane = tid&63;
  const int g16 = lane>>4, l16 = lane&15;
  const int lin = blockIdx.x;                 // 0..1023
  const int xcd = lin & 7, idx = lin >> 3;    // XCD = blockIdx % 8
  const int bh  = xcd*8 + (idx >> 4);         // 8 (b,h) groups per XCD
  const int qt  = idx & 15;
  const int b = bh >> 4, h = bh & 15;
  const int q0 = qt*128 + w*32;

  const bf16* Kb = Km + (size_t)b*2048*1024 + h*64;
  const bf16* Vb = Vt + (size_t)(b*16 + h)*64*2048;
  const int*  mb = msk + b*2048;

  // Q fragments loaded FIRST (oldest vmem -> their waits never drain staging)
  bf16x8 qf[2][2];
  #pragma unroll
  for (int qg=0;qg<2;qg++){
    const bf16* qp = Q + (size_t)(b*2048 + q0 + qg*16 + l16)*1024 + h*64 + g16*8;
    qf[qg][0] = *(const bf16x8*)qp;
    qf[qg][1] = *(const bf16x8*)(qp + 32);
  }
  asm volatile("" ::: "memory");              // pin issue order

  // staging addresses (loop-invariant); 8-slot XOR swizzle involution
  const int srow = w*16 + (lane>>3);
  const int sslot = ((lane&7) ^ (lane>>3)) * 8;
  const bf16* gK0 = Kb + (size_t)srow*1024 + sslot;
  const bf16* gK1 = gK0 + (size_t)8*1024;
  const bf16* gV0 = Vb + (size_t)srow*2048 + sslot;
  const bf16* gV1 = gV0 + (size_t)8*2048;

  auto stage = [&](int buf, int kv0){
    bf16* kl = &Ks[buf][w*1024];
    bf16* vl = &Vs[buf][w*1024];
    gload_lds16(gK0 + (size_t)kv0*1024, kl);
    gload_lds16(gK1 + (size_t)kv0*1024, kl + 512);
    gload_lds16(gV0 + kv0,              vl);
    gload_lds16(gV1 + kv0,              vl + 512);
  };

  // mask row -> LDS (2 x 4KB passes), then stage tiles 0 and 1
  {
    const int o0 = w*256 + lane*4;              // int offset, 16B/lane
    gload_lds16((const void*)(mb + o0),        (void*)(&Mq[w*256]));
    gload_lds16((const void*)(mb + 1024 + o0), (void*)(&Mq[1024 + w*256]));
  }
  stage(0, 0);
  stage(1, 64);
  asm volatile("s_waitcnt vmcnt(4)" ::: "memory"); // Q+mask+stage0 landed
  __builtin_amdgcn_s_barrier();
  asm volatile("" ::: "memory");

  // read offsets (loop-invariant)
  const int l7 = l16 & 7;
  const int kOff0 = l16*64 + ((g16     ^ l7) << 3);
  const int kOff1 = l16*64 + (((4+g16) ^ l7) << 3);
  int vOff[4];
  #pragma unroll
  for (int t=0;t<4;t++)
    vOff[t] = l16*64 + ((((t<<1) + (g16>>1)) ^ l7) << 3) + ((g16&1)<<2);

  float m_[2] = {-3e38f, -3e38f};
  float l_[2] = {0.f, 0.f};
  const f32x4 fz = {0.f,0.f,0.f,0.f};
  f32x4 xa[2][4];
  #pragma unroll
  for (int qg=0;qg<2;qg++)
    #pragma unroll
    for (int jd=0;jd<4;jd++) xa[qg][jd] = fz;

  int cur = 0;
  for (int it = 0; it < 32; ++it){
    const int kv0 = it*64;
    if (it < 30){
      const int pb = (cur+2 >= 3) ? cur-1 : cur+2;
      stage(pb, kv0 + 128);
    }
    // mask from LDS (broadcast reads, lgkm counter -- no vmcnt interference)
    int4 mm[4];
    #pragma unroll
    for (int t=0;t<4;t++) mm[t] = *(const int4*)&Mq[kv0 + t*16 + 4*g16];

    const bf16* ksb = &Ks[cur][0];
    const bf16* vsb = &Vs[cur][0];
    bf16x8 kk[4][2];
    #pragma unroll
    for (int t=0;t<4;t++){
      kk[t][0] = *(const bf16x8*)(ksb + t*1024 + kOff0);
      kk[t][1] = *(const bf16x8*)(ksb + t*1024 + kOff1);
    }
    f32x4 st[2][4];
    __builtin_amdgcn_s_setprio(1);
    #pragma unroll
    for (int t=0;t<4;t++){
      #pragma unroll
      for (int qg=0;qg<2;qg++){
        f32x4 a = fz;
        a = __builtin_amdgcn_mfma_f32_16x16x32_bf16(kk[t][0], qf[qg][0], a, 0,0,0);
        a = __builtin_amdgcn_mfma_f32_16x16x32_bf16(kk[t][1], qf[qg][1], a, 0,0,0);
        st[qg][t] = a;
      }
    }
    __builtin_amdgcn_s_setprio(0);
    bf16x4 vv[4][4];
    #pragma unroll
    for (int t=0;t<4;t++)
      #pragma unroll
      for (int jd=0;jd<4;jd++)
        vv[t][jd] = *(const bf16x4*)(vsb + jd*1024 + vOff[t]);
    bf16x4 pq[2][4];
    #pragma unroll
    for (int qg=0;qg<2;qg++){
      #pragma unroll
      for (int t=0;t<4;t++){
        st[qg][t][0] = (mm[t].x==0) ? -1.5e10f : st[qg][t][0];
        st[qg][t][1] = (mm[t].y==0) ? -1.5e10f : st[qg][t][1];
        st[qg][t][2] = (mm[t].z==0) ? -1.5e10f : st[qg][t][2];
        st[qg][t][3] = (mm[t].w==0) ? -1.5e10f : st[qg][t][3];
      }
      float a0 = fmaxf(st[qg][0][0], st[qg][0][1]);
      float a1 = fmaxf(st[qg][0][2], st[qg][0][3]);
      float a2 = fmaxf(st[qg][1][0], st[qg][1][1]);
      float a3 = fmaxf(st[qg][1][2], st[qg][1][3]);
      float a4 = fmaxf(st[qg][2][0], st[qg][2][1]);
      float a5 = fmaxf(st[qg][2][2], st[qg][2][3]);
      float a6 = fmaxf(st[qg][3][0], st[qg][3][1]);
      float a7 = fmaxf(st[qg][3][2], st[qg][3][3]);
      float tm = fmaxf(fmaxf(fmaxf(a0,a1), fmaxf(a2,a3)),
                       fmaxf(fmaxf(a4,a5), fmaxf(a6,a7)));
      if (!__all(tm <= m_[qg] + 8.f)){
        float fm = tm;
        fm = fmaxf(fm, __shfl_xor(fm, 16, 64));
        fm = fmaxf(fm, __shfl_xor(fm, 32, 64));
        const float mn = fmaxf(m_[qg], fm);
        const float sc = ex2(m_[qg] - mn);
        l_[qg] *= sc;
        #pragma unroll
        for (int jd=0;jd<4;jd++) xa[qg][jd] *= sc;
        m_[qg] = mn;
      }
      float rs0 = 0.f, rs1 = 0.f;
      #pragma unroll
      for (int t=0;t<4;t++){
        const float p0 = ex2(st[qg][t][0] - m_[qg]);
        const float p1 = ex2(st[qg][t][1] - m_[qg]);
        const float p2 = ex2(st[qg][t][2] - m_[qg]);
        const float p3 = ex2(st[qg][t][3] - m_[qg]);
        pq[qg][t][0] = (bf16)p0;
        pq[qg][t][1] = (bf16)p1;
        pq[qg][t][2] = (bf16)p2;
        pq[qg][t][3] = (bf16)p3;
        rs0 += p0 + p1;
        rs1 += p2 + p3;
      }
      l_[qg] += rs0 + rs1;
    }
    __builtin_amdgcn_s_setprio(1);
    #pragma unroll
    for (int t=0;t<4;t++){
      #pragma unroll
      for (int jd=0;jd<4;jd++){
        xa[0][jd] = mfma16bf(vv[t][jd], pq[0][t], xa[0][jd]);
        xa[1][jd] = mfma16bf(vv[t][jd], pq[1][t], xa[1][jd]);
      }
    }
    __builtin_amdgcn_s_setprio(0);
    if (it < 31){
      if (it < 30) asm volatile("s_waitcnt vmcnt(4)" ::: "memory"); // t+1 landed, t+2 in flight
      else         asm volatile("s_waitcnt vmcnt(0)" ::: "memory"); // drain last
      __builtin_amdgcn_s_barrier();
      asm volatile("" ::: "memory");
    }
    cur = (cur==2) ? 0 : cur+1;
  }

  // write O: lane holds q=l16 (per group), d = jd*16 + 4*g16 + r
  #pragma unroll
  for (int qg=0;qg<2;qg++){
    float lt = l_[qg];
    lt += __shfl_xor(lt, 16, 64);
    lt += __shfl_xor(lt, 32, 64);
    const float rl = 1.f / lt;
    const size_t row = (size_t)(b*2048 + q0 + qg*16 + l16);
    #pragma unroll
    for (int jd=0;jd<4;jd++){
      bf16x4 ov = { f2b(xa[qg][jd][0]*rl), f2b(xa[qg][jd][1]*rl),
                    f2b(xa[qg][jd][2]*rl), f2b(xa[qg][jd][3]*rl) };
      *(bf16x4*)(O + row*1024 + h*64 + jd*16 + 4*g16) = ov;
    }
  }
}

// ---------------- residual + layernorm (row = 1024) ----------------
__global__ __launch_bounds__(256) void addln_kernel(
    const float* __restrict__ X, const float* __restrict__ R,
    const float* __restrict__ g, const float* __restrict__ be,
    float* __restrict__ of, bf16* __restrict__ ob)
{
  const int row = blockIdx.x, tid = threadIdx.x;
  const float4 vx = ((const float4*)(X + (size_t)row*1024))[tid];
  const float4 vr = ((const float4*)(R + (size_t)row*1024))[tid];
  const float a0 = vx.x+vr.x, a1 = vx.y+vr.y, a2 = vx.z+vr.z, a3 = vx.w+vr.w;
  float s = a0+a1+a2+a3;
  float q = a0*a0 + a1*a1 + a2*a2 + a3*a3;
  #pragma unroll
  for (int off=1; off<64; off<<=1){
    s += __shfl_xor(s, off, 64);
    q += __shfl_xor(q, off, 64);
  }
  __shared__ float sb[8];
  if ((tid&63)==0){ sb[tid>>6] = s; sb[4+(tid>>6)] = q; }
  __syncthreads();
  s = sb[0]+sb[1]+sb[2]+sb[3];
  q = sb[4]+sb[5]+sb[6]+sb[7];
  const float mu = s*(1.f/1024.f);
  const float rs = rsqrtf(q*(1.f/1024.f) - mu*mu + 1e-5f);
  const float4 gg = ((const float4*)g)[tid];
  const float4 bb = ((const float4*)be)[tid];
  const float o0 = (a0-mu)*rs*gg.x + bb.x;
  const float o1 = (a1-mu)*rs*gg.y + bb.y;
  const float o2 = (a2-mu)*rs*gg.z + bb.z;
  const float o3 = (a3-mu)*rs*gg.w + bb.w;
  float4 o; o.x=o0; o.y=o1; o.z=o2; o.w=o3;
  ((float4*)(of + (size_t)row*1024))[tid] = o;
  if (ob){
    bf16x4 u = { f2b(o0), f2b(o1), f2b(o2), f2b(o3) };
    *(bf16x4*)(ob + (size_t)row*1024 + tid*4) = u;
  }
}

// ---------------- launch ----------------
extern "C" void kernel_launch(void* const* d_in, const int* in_sizes, int n_in,
                              void* d_out, int out_size, void* d_ws, size_t ws_size,
                              hipStream_t stream)
{
  const float* src  = (const float*)d_in[0];
  const int*   mask = (const int*)  d_in[1];
  const float* Wq = (const float*)d_in[2];  const float* bq = (const float*)d_in[3];
  const float* Wk = (const float*)d_in[4];  const float* bk = (const float*)d_in[5];
  const float* Wv = (const float*)d_in[6];  const float* bv = (const float*)d_in[7];
  const float* Wo = (const float*)d_in[8];  const float* bo = (const float*)d_in[9];
  const float* W1 = (const float*)d_in[10]; const float* b1 = (const float*)d_in[11];
  const float* W2 = (const float*)d_in[12]; const float* b2 = (const float*)d_in[13];
  const float* g1 = (const float*)d_in[14]; const float* be1 = (const float*)d_in[15];
  const float* g2 = (const float*)d_in[16]; const float* be2 = (const float*)d_in[17];

  char* ws = (char*)d_ws;
  const size_t MB = 1u<<20;
  bf16* srcb  = (bf16*)(ws + 0*MB);    // 16 MB  [dead after QKV gemm]
  bf16* Wqkvt = (bf16*)(ws + 16*MB);   // 6 MB   (Q rows 0-1023, K 1024-2047, V 2048-3071)
  bf16* Wot   = (bf16*)(ws + 22*MB);   // 2 MB
  bf16* W1t   = (bf16*)(ws + 24*MB);   // 8 MB
  bf16* W2t   = (bf16*)(ws + 32*MB);   // 8 MB
  bf16* Qb    = (bf16*)(ws + 40*MB);   // 16 MB [dead after attn]
  bf16* Kb    = (bf16*)(ws + 56*MB);   // 16 MB [dead after attn]
  bf16* Vtb   = (bf16*)(ws + 72*MB);   // 16 MB [dead after attn]
  bf16* AO    = (bf16*)(ws + 88*MB);   // 16 MB [dead after O-proj]
  float* X1   = (float*)(ws + 40*MB);  // 32 MB over Qb+Kb
  float* S1F  = (float*)(ws + 72*MB);  // 32 MB over Vtb+AO
  bf16*  S1B  = (bf16*)(ws + 0*MB);    // 16 MB over srcb
  bf16*  H1   = (bf16*)(ws + 104*MB);  // 64 MB
  float* F2   = (float*)(ws + 40*MB);  // 32 MB over X1 (dead after LN1)

  const float QSC = 0.18033688011112042f;   // 0.125 * log2(e)

  // cast + all weight transposes in one launch
  prep_kernel<<<20480, 256, 0, stream>>>(src, srcb, Wq, Wk, Wv, Wo, W1, W2,
                                         Wqkvt, Wot, W1t, W2t);

  // fused QKV projection (N=3072, 1536 blocks; Q pre-scaled into exp2 domain)
  gemm_bt_kernel<4><<<dim3(24,64), 256, 0, stream>>>(
      srcb, Wqkvt, bq, Qb, 8192, 3072, 1024, QSC, bk, bv, Kb, Vtb);

  // attention
  attn_kernel<<<1024, 256, 0, stream>>>(Qb, Kb, Vtb, mask, AO);

  // output projection + LN1
  gemm_bt_kernel<0><<<dim3(8,64),  256, 0, stream>>>(AO, Wot, bo, X1, 8192, 1024, 1024, 1.f,
                                                     nullptr, nullptr, nullptr, nullptr);
  addln_kernel<<<8192, 256, 0, stream>>>(X1, src, g1, be1, S1F, S1B);

  // FFN (swish) + LN2 -> d_out
  gemm_bt_kernel<2><<<dim3(32,64), 256, 0, stream>>>(S1B, W1t, b1, H1, 8192, 4096, 1024, 1.f,
                                                     nullptr, nullptr, nullptr, nullptr);
  gemm_bt_kernel<0><<<dim3(8,64),  256, 0, stream>>>(H1,  W2t, b2, F2, 8192, 1024, 4096, 1.f,
                                                     nullptr, nullptr, nullptr, nullptr);
  addln_kernel<<<8192, 256, 0, stream>>>(F2, S1F, g2, be2, (float*)d_out, (bf16*)nullptr);
}

// Round 7
// 486.171 us; speedup vs baseline: 1.4996x; 1.0144x over previous
//
#include <hip/hip_runtime.h>
#include <stdint.h>

// EncoderLayer on MI355X (gfx950), bf16 MFMA pipeline.
// B=4, S=2048, HID=1024, HEADS=16, HD=64, PF=4096. M = B*S = 8192.

typedef __bf16 bf16;
typedef __bf16 bf16x4 __attribute__((ext_vector_type(4)));
typedef __bf16 bf16x8 __attribute__((ext_vector_type(8)));
typedef short  s16x4  __attribute__((ext_vector_type(4)));
typedef float  f32x4  __attribute__((ext_vector_type(4)));

__device__ __forceinline__ bf16 f2b(float x){
  uint32_t u = __builtin_bit_cast(uint32_t, x);
  uint32_t r = (u + 0x7FFFu + ((u >> 16) & 1u)) >> 16;   // RNE
  return __builtin_bit_cast(bf16, (uint16_t)r);
}

__device__ __forceinline__ float ex2(float x){
#if __has_builtin(__builtin_amdgcn_exp2f)
  return __builtin_amdgcn_exp2f(x);
#else
  return __exp2f(x);
#endif
}

// 16x16x16 bf16 MFMA (A,B: 4 bf16 / 2 VGPRs each; D: 4 f32)
__device__ __forceinline__ f32x4 mfma16bf(bf16x4 a, bf16x4 b, f32x4 c){
#if __has_builtin(__builtin_amdgcn_mfma_f32_16x16x16_bf16)
  return __builtin_amdgcn_mfma_f32_16x16x16_bf16(a, b, c, 0, 0, 0);
#elif __has_builtin(__builtin_amdgcn_mfma_f32_16x16x16bf16_1k)
  return __builtin_amdgcn_mfma_f32_16x16x16bf16_1k(
      __builtin_bit_cast(s16x4, a), __builtin_bit_cast(s16x4, b), c, 0, 0, 0);
#else
  f32x4 d = c;
  asm volatile("v_mfma_f32_16x16x16_bf16 %0, %1, %2, %0"
               : "+v"(d)
               : "v"(__builtin_bit_cast(s16x4, a)), "v"(__builtin_bit_cast(s16x4, b)));
  return d;
#endif
}

// async global->LDS, 16B per lane (LDS dest = wave-uniform base + lane*16,
// global source is per-lane)
__device__ __forceinline__ void gload_lds16(const void* g, void* l){
  __builtin_amdgcn_global_load_lds(
      (const __attribute__((address_space(1))) void*)g,
      (__attribute__((address_space(3))) void*)l, 16, 0, 0);
}

#define PH_BAR() do{ asm volatile("" ::: "memory"); \
                     __builtin_amdgcn_s_barrier();  \
                     asm volatile("" ::: "memory"); }while(0)

// ---------------- prep: src cast + all 6 weight transposes, one launch ------
__global__ __launch_bounds__(256) void prep_kernel(
    const float* __restrict__ src, bf16* __restrict__ srcb,
    const float* __restrict__ Wq, const float* __restrict__ Wk,
    const float* __restrict__ Wv, const float* __restrict__ Wo,
    const float* __restrict__ W1, const float* __restrict__ W2,
    bf16* __restrict__ Wqkvt, bf16* __restrict__ Wot,
    bf16* __restrict__ W1t,  bf16* __restrict__ W2t)
{
  __shared__ float t[32][33];
  const int bb = blockIdx.x, tid = threadIdx.x;
  if (bb < 8192){
    const int i = bb*256 + tid;
    const float4 v = ((const float4*)src)[i];
    bf16x4 u = { f2b(v.x), f2b(v.y), f2b(v.z), f2b(v.w) };
    *(bf16x4*)(srcb + (size_t)i*4) = u;
    return;
  }
  const int idx = bb - 8192;
  const float* W; bf16* Wt; int K, N, bx, by;
  if (idx < 3072){
    const int r = idx >> 10, j = idx & 1023;
    W = (r==0)?Wq:(r==1)?Wk:Wv; Wt = Wqkvt + (size_t)r*1024*1024;
    K = 1024; N = 1024; bx = j & 31; by = j >> 5;
  } else if (idx < 4096){
    const int j = idx - 3072;
    W = Wo; Wt = Wot; K = 1024; N = 1024; bx = j & 31; by = j >> 5;
  } else if (idx < 8192){
    const int j = idx - 4096;
    W = W1; Wt = W1t; K = 1024; N = 4096; bx = j & 127; by = j >> 7;
  } else {
    const int j = idx - 8192;
    W = W2; Wt = W2t; K = 4096; N = 1024; bx = j & 31; by = j >> 5;
  }
  const int x = tid & 31, y = tid >> 5;
  const int n0 = bx*32, k0 = by*32;
  #pragma unroll
  for (int r=0;r<4;r++) t[y+8*r][x] = W[(size_t)(k0+y+8*r)*N + n0+x];
  __syncthreads();
  #pragma unroll
  for (int r=0;r<4;r++) Wt[(size_t)(n0+y+8*r)*K + k0+x] = f2b(t[x][y+8*r]);
}

// ---------------- 8-phase 256x256 GEMM (T2+T3+T4+T5 template) --------------
// C = A[M][K] * Bt[N][K]^T + bias. BM=BN=256, BK=64, 8 waves (2M x 4N),
// wave output 128x64 (8x4 frags of 16x16x32). LDS 128 KiB: [buf][half][128][64]
// per operand, linear dest + inverse-XOR'd global source + XOR'd ds_read
// (slot ^= row&7). Per phase: {ds_read subtile; stage 1 half-tile (2 gload);
// [vmcnt(4) @P4/P8]; barrier; setprio1; 16 MFMA; setprio0; barrier}.
// Stage slots: P1:t+1.A1 P2:t+1.B1 P3:t+2.B0 P4:t+2.A0 P5:t+2.A1 P6:t+2.B1
// P7:t+3.B0 P8:t+3.A0  (each region's last ds_read >=1 barrier earlier;
// vmcnt(4) forces the needed tile's halves complete 1 phase before use).
// OMODE: 2=bf16+swish, 4=fused QKV (C=Q scaled, C2=K, C3=V^T)
template<int OMODE>
__global__ __launch_bounds__(512, 2) void gemm8_kernel(
    const bf16* __restrict__ A, const bf16* __restrict__ Bt,
    const float* __restrict__ bias, void* __restrict__ C,
    int M, int N, int K, float oscale,
    const float* __restrict__ bias2, const float* __restrict__ bias3,
    void* __restrict__ C2, void* __restrict__ C3)
{
  __shared__ bf16 Al[2][2][128][64];   // [buf][half][row][col] 64 KiB
  __shared__ bf16 Bl[2][2][128][64];   // 64 KiB

  const int tid = threadIdx.x;
  const int w = tid >> 6, lane = tid & 63;
  const int wr = w >> 2, wc = w & 3;            // 2M x 4N wave grid
  const int g16 = lane >> 4, l16 = lane & 15;
  const int m0 = blockIdx.y*256, n0 = blockIdx.x*256;
  const int NT = K >> 6;                        // K-tiles of 64
  const int NI = NT >> 1;

  const bf16* Asrc = A  + (size_t)m0*K;
  const bf16* Bsrc = Bt + (size_t)n0*K;
  const int w8 = w << 3;
  const int sr = lane >> 3;                     // row-within-8
  const int sslot = ((lane & 7) ^ (sr & 7)) * 8;// inverse-swizzled src slot (elems)

  f32x4 acc[8][4];
  const f32x4 fz = {0.f,0.f,0.f,0.f};
  #pragma unroll
  for (int i=0;i<8;i++)
    #pragma unroll
    for (int j=0;j<4;j++) acc[i][j] = fz;

  auto stageA = [&](int tile, int half, int buf){
    if (tile < NT){
      const bf16* s0 = Asrc + (size_t)(half*128 + w8 + sr)*K + tile*64 + sslot;
      gload_lds16(s0,                  &Al[buf][half][w8][0]);
      gload_lds16(s0 + (size_t)64*K,   &Al[buf][half][64 + w8][0]);
    }
  };
  auto stageB = [&](int tile, int half, int buf){
    if (tile < NT){
      const bf16* s0 = Bsrc + (size_t)(half*128 + w8 + sr)*K + tile*64 + sslot;
      gload_lds16(s0,                  &Bl[buf][half][w8][0]);
      gload_lds16(s0 + (size_t)64*K,   &Bl[buf][half][64 + w8][0]);
    }
  };
  auto readA = [&](int buf, int mh, bf16x8 (&a)[4][2]){
    const bf16* base = &Al[buf][wr][0][0];
    #pragma unroll
    for (int fm=0;fm<4;fm++){
      const int la = mh*64 + fm*16 + l16;
      #pragma unroll
      for (int kk=0;kk<2;kk++)
        a[fm][kk] = *(const bf16x8*)(base + la*64 + ((((kk<<2)+g16) ^ (l16&7))<<3));
    }
  };
  auto readB = [&](int buf, int nh, bf16x8 (&b)[2][2]){
    const bf16* base = &Bl[buf][wc>>1][0][0];
    #pragma unroll
    for (int fn=0;fn<2;fn++){
      const int lb = (wc&1)*64 + nh*32 + fn*16 + l16;
      #pragma unroll
      for (int kk=0;kk<2;kk++)
        b[fn][kk] = *(const bf16x8*)(base + lb*64 + ((((kk<<2)+g16) ^ (l16&7))<<3));
    }
  };
  auto MM = [&](int mh, int nh, bf16x8 (&a)[4][2], bf16x8 (&b)[2][2]){
    __builtin_amdgcn_s_setprio(1);
    #pragma unroll
    for (int kk=0;kk<2;kk++)
      #pragma unroll
      for (int fm=0;fm<4;fm++)
        #pragma unroll
        for (int fn=0;fn<2;fn++)
          acc[mh*4+fm][nh*2+fn] = __builtin_amdgcn_mfma_f32_16x16x32_bf16(
              a[fm][kk], b[fn][kk], acc[mh*4+fm][nh*2+fn], 0, 0, 0);
    __builtin_amdgcn_s_setprio(0);
  };

  // prologue: tile0 {B0,A0,A1,B1} + tile1 {B0,A0}; wait tile0 landed.
  stageB(0,0,0); stageA(0,0,0); stageA(0,1,0); stageB(0,1,0);
  stageB(1,0,1); stageA(1,0,1);
  asm volatile("s_waitcnt vmcnt(4)" ::: "memory");
  __builtin_amdgcn_s_barrier();
  asm volatile("" ::: "memory");

  for (int i=0;i<NI;++i){
    const int t1 = 2*i+1, t2 = 2*i+2, t3 = 2*i+3;
    bf16x8 aF[4][2], bF0[2][2], bF1[2][2];
    // P1
    readA(0,0,aF); readB(0,0,bF0);
    stageA(t1,1,1);
    PH_BAR(); MM(0,0,aF,bF0); PH_BAR();
    // P2
    readB(0,1,bF1);
    stageB(t1,1,1);
    PH_BAR(); MM(0,1,aF,bF1); PH_BAR();
    // P3
    readA(0,1,aF);
    stageB(t2,0,0);
    PH_BAR(); MM(1,1,aF,bF1); PH_BAR();
    // P4
    stageA(t2,0,0);
    asm volatile("s_waitcnt vmcnt(4)" ::: "memory");
    PH_BAR(); MM(1,0,aF,bF0); PH_BAR();
    // P5
    readA(1,0,aF); readB(1,0,bF0);
    stageA(t2,1,0);
    PH_BAR(); MM(0,0,aF,bF0); PH_BAR();
    // P6
    readB(1,1,bF1);
    stageB(t2,1,0);
    PH_BAR(); MM(0,1,aF,bF1); PH_BAR();
    // P7
    readA(1,1,aF);
    stageB(t3,0,1);
    PH_BAR(); MM(1,1,aF,bF1); PH_BAR();
    // P8
    stageA(t3,0,1);
    asm volatile("s_waitcnt vmcnt(4)" ::: "memory");
    PH_BAR(); MM(1,0,aF,bF0); PH_BAR();
  }

  // epilogue: D[i][j]: j = lane&15 (N), i = 4*(lane>>4)+reg (M)
  const int colb = n0 + wc*64 + l16;
  if constexpr (OMODE==4){
    const int region = n0 >> 10;                // 256-tile lies in one region
    const float* bs = (region==0)? bias : (region==1)? bias2 : bias3;
    const int colbase = region << 10;
    #pragma unroll
    for (int an=0;an<4;an++){
      const int cl = colb + an*16 - colbase;
      const float bv = bs[cl];
      #pragma unroll
      for (int am=0;am<8;am++){
        const int rbase = m0 + wr*128 + am*16 + g16*4;
        #pragma unroll
        for (int r=0;r<4;r++){
          const float v = acc[am][an][r] + bv;
          const size_t row = (size_t)(rbase + r);
          if (region==0)      ((bf16*)C )[row*1024 + cl] = f2b(v * oscale);
          else if (region==1) ((bf16*)C2)[row*1024 + cl] = f2b(v);
          else {
            const size_t bq = row >> 11, s = row & 2047;
            ((bf16*)C3)[(bq*1024 + (size_t)cl)*2048 + s] = f2b(v);
          }
        }
      }
    }
  } else {
    #pragma unroll
    for (int an=0;an<4;an++){
      const int col = colb + an*16;
      const float bv = bias[col];
      #pragma unroll
      for (int am=0;am<8;am++){
        const int rbase = m0 + wr*128 + am*16 + g16*4;
        #pragma unroll
        for (int r=0;r<4;r++){
          float v = acc[am][an][r] + bv;
          const size_t row = (size_t)(rbase + r);
          if constexpr (OMODE==2){
            v = v / (1.f + __expf(-v));         // swish
            ((bf16*)C)[row*N + col] = f2b(v);
          } else {
            ((float*)C)[row*N + col] = v;
          }
        }
      }
    }
  }
}

// ---------------- GEMM 128x128 (known-good) for N=1024 shapes --------------
// OMODE: 0=f32 out
template<int OMODE>
__global__ __launch_bounds__(256) void gemm_bt_kernel(
    const bf16* __restrict__ A, const bf16* __restrict__ Bt,
    const float* __restrict__ bias, void* __restrict__ C,
    int M, int N, int K, float oscale)
{
  __shared__ bf16 As[128*32];
  __shared__ bf16 Bs[128*32];
  const int tid = threadIdx.x;
  const int w = tid >> 6, lane = tid & 63;
  const int wr = w >> 1, wc = w & 1;
  const int g16 = lane >> 4, l16 = lane & 15;
  const int m0 = blockIdx.y*128, n0 = blockIdx.x*128;

  const int ar = tid >> 2, asl = tid & 3;
  const bf16* gA = A  + (size_t)(m0+ar)*K + asl*8;
  const bf16* gB = Bt + (size_t)(n0+ar)*K + asl*8;
  const int sw0 = (ar>>1)&3;
  const int la = ar*32      + ((asl ^ sw0)<<3);
  const int lb = (ar+64)*32 + ((asl ^ sw0)<<3);

  f32x4 acc[4][4];
  const f32x4 fz = {0.f,0.f,0.f,0.f};
  #pragma unroll
  for (int m=0;m<4;m++)
    #pragma unroll
    for (int n=0;n<4;n++) acc[m][n] = fz;

  bf16x8 ra0 = *(const bf16x8*)gA;
  bf16x8 ra1 = *(const bf16x8*)(gA + (size_t)64*K);
  bf16x8 rb0 = *(const bf16x8*)gB;
  bf16x8 rb1 = *(const bf16x8*)(gB + (size_t)64*K);

  for (int k0=0; k0<K; k0+=32){
    __syncthreads();
    *(bf16x8*)&As[la] = ra0;
    *(bf16x8*)&As[lb] = ra1;
    *(bf16x8*)&Bs[la] = rb0;
    *(bf16x8*)&Bs[lb] = rb1;
    __syncthreads();
    if (k0 + 32 < K){
      ra0 = *(const bf16x8*)(gA + k0+32);
      ra1 = *(const bf16x8*)(gA + (size_t)64*K + k0+32);
      rb0 = *(const bf16x8*)(gB + k0+32);
      rb1 = *(const bf16x8*)(gB + (size_t)64*K + k0+32);
    }
    bf16x8 af[4], bfv[4];
    #pragma unroll
    for (int m=0;m<4;m++){
      const int r = wr*64 + m*16 + l16;
      af[m] = *(const bf16x8*)&As[r*32 + ((g16 ^ ((r>>1)&3))<<3)];
    }
    #pragma unroll
    for (int n=0;n<4;n++){
      const int r = wc*64 + n*16 + l16;
      bfv[n] = *(const bf16x8*)&Bs[r*32 + ((g16 ^ ((r>>1)&3))<<3)];
    }
    #pragma unroll
    for (int m=0;m<4;m++)
      #pragma unroll
      for (int n=0;n<4;n++)
        acc[m][n] = __builtin_amdgcn_mfma_f32_16x16x32_bf16(af[m], bfv[n], acc[m][n], 0, 0, 0);
  }

  const int cb = n0 + wc*64 + l16;
  #pragma unroll
  for (int n=0;n<4;n++){
    const int col = cb + n*16;
    const float bv = bias[col];
    #pragma unroll
    for (int m=0;m<4;m++){
      const int rbase = m0 + wr*64 + m*16 + g16*4;
      #pragma unroll
      for (int r=0;r<4;r++){
        float v = acc[m][n][r] + bv;
        const size_t row = (size_t)(rbase + r);
        ((float*)C)[row*N + col] = v;
      }
    }
  }
}

// ---------------- flash attention (unchanged from round 6) -----------------
__global__ __launch_bounds__(256) void attn_kernel(
    const bf16* __restrict__ Q, const bf16* __restrict__ Km,
    const bf16* __restrict__ Vt, const int* __restrict__ msk,
    bf16* __restrict__ O)
{
  __shared__ bf16 Ks[3][64*64];
  __shared__ bf16 Vs[3][64*64];
  __shared__ int  Mq[2048];

  const int tid = threadIdx.x;
  const int w = tid>>6, lane = tid&63;
  const int g16 = lane>>4, l16 = lane&15;
  const int lin = blockIdx.x;
  const int xcd = lin & 7, idx = lin >> 3;
  const int bh  = xcd*8 + (idx >> 4);
  const int qt  = idx & 15;
  const int b = bh >> 4, h = bh & 15;
  const int q0 = qt*128 + w*32;

  const bf16* Kb = Km + (size_t)b*2048*1024 + h*64;
  const bf16* Vb = Vt + (size_t)(b*16 + h)*64*2048;
  const int*  mb = msk + b*2048;

  bf16x8 qf[2][2];
  #pragma unroll
  for (int qg=0;qg<2;qg++){
    const bf16* qp = Q + (size_t)(b*2048 + q0 + qg*16 + l16)*1024 + h*64 + g16*8;
    qf[qg][0] = *(const bf16x8*)qp;
    qf[qg][1] = *(const bf16x8*)(qp + 32);
  }
  asm volatile("" ::: "memory");

  const int srow = w*16 + (lane>>3);
  const int sslot = ((lane&7) ^ (lane>>3)) * 8;
  const bf16* gK0 = Kb + (size_t)srow*1024 + sslot;
  const bf16* gK1 = gK0 + (size_t)8*1024;
  const bf16* gV0 = Vb + (size_t)srow*2048 + sslot;
  const bf16* gV1 = gV0 + (size_t)8*2048;

  auto stage = [&](int buf, int kv0){
    bf16* kl = &Ks[buf][w*1024];
    bf16* vl = &Vs[buf][w*1024];
    gload_lds16(gK0 + (size_t)kv0*1024, kl);
    gload_lds16(gK1 + (size_t)kv0*1024, kl + 512);
    gload_lds16(gV0 + kv0,              vl);
    gload_lds16(gV1 + kv0,              vl + 512);
  };

  {
    const int o0 = w*256 + lane*4;
    gload_lds16((const void*)(mb + o0),        (void*)(&Mq[w*256]));
    gload_lds16((const void*)(mb + 1024 + o0), (void*)(&Mq[1024 + w*256]));
  }
  stage(0, 0);
  stage(1, 64);
  asm volatile("s_waitcnt vmcnt(4)" ::: "memory");
  __builtin_amdgcn_s_barrier();
  asm volatile("" ::: "memory");

  const int l7 = l16 & 7;
  const int kOff0 = l16*64 + ((g16     ^ l7) << 3);
  const int kOff1 = l16*64 + (((4+g16) ^ l7) << 3);
  int vOff[4];
  #pragma unroll
  for (int t=0;t<4;t++)
    vOff[t] = l16*64 + ((((t<<1) + (g16>>1)) ^ l7) << 3) + ((g16&1)<<2);

  float m_[2] = {-3e38f, -3e38f};
  float l_[2] = {0.f, 0.f};
  const f32x4 fz = {0.f,0.f,0.f,0.f};
  f32x4 xa[2][4];
  #pragma unroll
  for (int qg=0;qg<2;qg++)
    #pragma unroll
    for (int jd=0;jd<4;jd++) xa[qg][jd] = fz;

  int cur = 0;
  for (int it = 0; it < 32; ++it){
    const int kv0 = it*64;
    if (it < 30){
      const int pb = (cur+2 >= 3) ? cur-1 : cur+2;
      stage(pb, kv0 + 128);
    }
    int4 mm[4];
    #pragma unroll
    for (int t=0;t<4;t++) mm[t] = *(const int4*)&Mq[kv0 + t*16 + 4*g16];

    const bf16* ksb = &Ks[cur][0];
    const bf16* vsb = &Vs[cur][0];
    bf16x8 kk[4][2];
    #pragma unroll
    for (int t=0;t<4;t++){
      kk[t][0] = *(const bf16x8*)(ksb + t*1024 + kOff0);
      kk[t][1] = *(const bf16x8*)(ksb + t*1024 + kOff1);
    }
    f32x4 st[2][4];
    __builtin_amdgcn_s_setprio(1);
    #pragma unroll
    for (int t=0;t<4;t++){
      #pragma unroll
      for (int qg=0;qg<2;qg++){
        f32x4 a = fz;
        a = __builtin_amdgcn_mfma_f32_16x16x32_bf16(kk[t][0], qf[qg][0], a, 0,0,0);
        a = __builtin_amdgcn_mfma_f32_16x16x32_bf16(kk[t][1], qf[qg][1], a, 0,0,0);
        st[qg][t] = a;
      }
    }
    __builtin_amdgcn_s_setprio(0);
    bf16x4 vv[4][4];
    #pragma unroll
    for (int t=0;t<4;t++)
      #pragma unroll
      for (int jd=0;jd<4;jd++)
        vv[t][jd] = *(const bf16x4*)(vsb + jd*1024 + vOff[t]);
    bf16x4 pq[2][4];
    #pragma unroll
    for (int qg=0;qg<2;qg++){
      #pragma unroll
      for (int t=0;t<4;t++){
        st[qg][t][0] = (mm[t].x==0) ? -1.5e10f : st[qg][t][0];
        st[qg][t][1] = (mm[t].y==0) ? -1.5e10f : st[qg][t][1];
        st[qg][t][2] = (mm[t].z==0) ? -1.5e10f : st[qg][t][2];
        st[qg][t][3] = (mm[t].w==0) ? -1.5e10f : st[qg][t][3];
      }
      float a0 = fmaxf(st[qg][0][0], st[qg][0][1]);
      float a1 = fmaxf(st[qg][0][2], st[qg][0][3]);
      float a2 = fmaxf(st[qg][1][0], st[qg][1][1]);
      float a3 = fmaxf(st[qg][1][2], st[qg][1][3]);
      float a4 = fmaxf(st[qg][2][0], st[qg][2][1]);
      float a5 = fmaxf(st[qg][2][2], st[qg][2][3]);
      float a6 = fmaxf(st[qg][3][0], st[qg][3][1]);
      float a7 = fmaxf(st[qg][3][2], st[qg][3][3]);
      float tm = fmaxf(fmaxf(fmaxf(a0,a1), fmaxf(a2,a3)),
                       fmaxf(fmaxf(a4,a5), fmaxf(a6,a7)));
      if (!__all(tm <= m_[qg] + 8.f)){
        float fm = tm;
        fm = fmaxf(fm, __shfl_xor(fm, 16, 64));
        fm = fmaxf(fm, __shfl_xor(fm, 32, 64));
        const float mn = fmaxf(m_[qg], fm);
        const float sc = ex2(m_[qg] - mn);
        l_[qg] *= sc;
        #pragma unroll
        for (int jd=0;jd<4;jd++) xa[qg][jd] *= sc;
        m_[qg] = mn;
      }
      float rs0 = 0.f, rs1 = 0.f;
      #pragma unroll
      for (int t=0;t<4;t++){
        const float p0 = ex2(st[qg][t][0] - m_[qg]);
        const float p1 = ex2(st[qg][t][1] - m_[qg]);
        const float p2 = ex2(st[qg][t][2] - m_[qg]);
        const float p3 = ex2(st[qg][t][3] - m_[qg]);
        pq[qg][t][0] = (bf16)p0;
        pq[qg][t][1] = (bf16)p1;
        pq[qg][t][2] = (bf16)p2;
        pq[qg][t][3] = (bf16)p3;
        rs0 += p0 + p1;
        rs1 += p2 + p3;
      }
      l_[qg] += rs0 + rs1;
    }
    __builtin_amdgcn_s_setprio(1);
    #pragma unroll
    for (int t=0;t<4;t++){
      #pragma unroll
      for (int jd=0;jd<4;jd++){
        xa[0][jd] = mfma16bf(vv[t][jd], pq[0][t], xa[0][jd]);
        xa[1][jd] = mfma16bf(vv[t][jd], pq[1][t], xa[1][jd]);
      }
    }
    __builtin_amdgcn_s_setprio(0);
    if (it < 31){
      if (it < 30) asm volatile("s_waitcnt vmcnt(4)" ::: "memory");
      else         asm volatile("s_waitcnt vmcnt(0)" ::: "memory");
      __builtin_amdgcn_s_barrier();
      asm volatile("" ::: "memory");
    }
    cur = (cur==2) ? 0 : cur+1;
  }

  #pragma unroll
  for (int qg=0;qg<2;qg++){
    float lt = l_[qg];
    lt += __shfl_xor(lt, 16, 64);
    lt += __shfl_xor(lt, 32, 64);
    const float rl = 1.f / lt;
    const size_t row = (size_t)(b*2048 + q0 + qg*16 + l16);
    #pragma unroll
    for (int jd=0;jd<4;jd++){
      bf16x4 ov = { f2b(xa[qg][jd][0]*rl), f2b(xa[qg][jd][1]*rl),
                    f2b(xa[qg][jd][2]*rl), f2b(xa[qg][jd][3]*rl) };
      *(bf16x4*)(O + row*1024 + h*64 + jd*16 + 4*g16) = ov;
    }
  }
}

// ---------------- residual + layernorm (row = 1024) ----------------
__global__ __launch_bounds__(256) void addln_kernel(
    const float* __restrict__ X, const float* __restrict__ R,
    const float* __restrict__ g, const float* __restrict__ be,
    float* __restrict__ of, bf16* __restrict__ ob)
{
  const int row = blockIdx.x, tid = threadIdx.x;
  const float4 vx = ((const float4*)(X + (size_t)row*1024))[tid];
  const float4 vr = ((const float4*)(R + (size_t)row*1024))[tid];
  const float a0 = vx.x+vr.x, a1 = vx.y+vr.y, a2 = vx.z+vr.z, a3 = vx.w+vr.w;
  float s = a0+a1+a2+a3;
  float q = a0*a0 + a1*a1 + a2*a2 + a3*a3;
  #pragma unroll
  for (int off=1; off<64; off<<=1){
    s += __shfl_xor(s, off, 64);
    q += __shfl_xor(q, off, 64);
  }
  __shared__ float sb[8];
  if ((tid&63)==0){ sb[tid>>6] = s; sb[4+(tid>>6)] = q; }
  __syncthreads();
  s = sb[0]+sb[1]+sb[2]+sb[3];
  q = sb[4]+sb[5]+sb[6]+sb[7];
  const float mu = s*(1.f/1024.f);
  const float rs = rsqrtf(q*(1.f/1024.f) - mu*mu + 1e-5f);
  const float4 gg = ((const float4*)g)[tid];
  const float4 bb = ((const float4*)be)[tid];
  const float o0 = (a0-mu)*rs*gg.x + bb.x;
  const float o1 = (a1-mu)*rs*gg.y + bb.y;
  const float o2 = (a2-mu)*rs*gg.z + bb.z;
  const float o3 = (a3-mu)*rs*gg.w + bb.w;
  float4 o; o.x=o0; o.y=o1; o.z=o2; o.w=o3;
  ((float4*)(of + (size_t)row*1024))[tid] = o;
  if (ob){
    bf16x4 u = { f2b(o0), f2b(o1), f2b(o2), f2b(o3) };
    *(bf16x4*)(ob + (size_t)row*1024 + tid*4) = u;
  }
}

// ---------------- launch ----------------
extern "C" void kernel_launch(void* const* d_in, const int* in_sizes, int n_in,
                              void* d_out, int out_size, void* d_ws, size_t ws_size,
                              hipStream_t stream)
{
  const float* src  = (const float*)d_in[0];
  const int*   mask = (const int*)  d_in[1];
  const float* Wq = (const float*)d_in[2];  const float* bq = (const float*)d_in[3];
  const float* Wk = (const float*)d_in[4];  const float* bk = (const float*)d_in[5];
  const float* Wv = (const float*)d_in[6];  const float* bv = (const float*)d_in[7];
  const float* Wo = (const float*)d_in[8];  const float* bo = (const float*)d_in[9];
  const float* W1 = (const float*)d_in[10]; const float* b1 = (const float*)d_in[11];
  const float* W2 = (const float*)d_in[12]; const float* b2 = (const float*)d_in[13];
  const float* g1 = (const float*)d_in[14]; const float* be1 = (const float*)d_in[15];
  const float* g2 = (const float*)d_in[16]; const float* be2 = (const float*)d_in[17];

  char* ws = (char*)d_ws;
  const size_t MB = 1u<<20;
  bf16* srcb  = (bf16*)(ws + 0*MB);    // 16 MB  [dead after QKV gemm]
  bf16* Wqkvt = (bf16*)(ws + 16*MB);   // 6 MB
  bf16* Wot   = (bf16*)(ws + 22*MB);   // 2 MB
  bf16* W1t   = (bf16*)(ws + 24*MB);   // 8 MB
  bf16* W2t   = (bf16*)(ws + 32*MB);   // 8 MB
  bf16* Qb    = (bf16*)(ws + 40*MB);   // 16 MB [dead after attn]
  bf16* Kb    = (bf16*)(ws + 56*MB);   // 16 MB [dead after attn]
  bf16* Vtb   = (bf16*)(ws + 72*MB);   // 16 MB [dead after attn]
  bf16* AO    = (bf16*)(ws + 88*MB);   // 16 MB [dead after O-proj]
  float* X1   = (float*)(ws + 40*MB);  // 32 MB over Qb+Kb
  float* S1F  = (float*)(ws + 72*MB);  // 32 MB over Vtb+AO
  bf16*  S1B  = (bf16*)(ws + 0*MB);    // 16 MB over srcb
  bf16*  H1   = (bf16*)(ws + 104*MB);  // 64 MB
  float* F2   = (float*)(ws + 40*MB);  // 32 MB over X1 (dead after LN1)

  const float QSC = 0.18033688011112042f;   // 0.125 * log2(e)

  // cast + all weight transposes in one launch
  prep_kernel<<<20480, 256, 0, stream>>>(src, srcb, Wq, Wk, Wv, Wo, W1, W2,
                                         Wqkvt, Wot, W1t, W2t);

  // fused QKV projection: 8-phase 256^2 (N=3072)
  gemm8_kernel<4><<<dim3(12,32), 512, 0, stream>>>(
      srcb, Wqkvt, bq, Qb, 8192, 3072, 1024, QSC, bk, bv, Kb, Vtb);

  // attention
  attn_kernel<<<1024, 256, 0, stream>>>(Qb, Kb, Vtb, mask, AO);

  // output projection + LN1 (128^2 kernel: N=1024 grid shape)
  gemm_bt_kernel<0><<<dim3(8,64),  256, 0, stream>>>(AO, Wot, bo, X1, 8192, 1024, 1024, 1.f);
  addln_kernel<<<8192, 256, 0, stream>>>(X1, src, g1, be1, S1F, S1B);

  // FFN1: 8-phase 256^2 (N=4096, swish) ; FFN2: 128^2 (N=1024, K=4096)
  gemm8_kernel<2><<<dim3(16,32), 512, 0, stream>>>(
      S1B, W1t, b1, H1, 8192, 4096, 1024, 1.f, nullptr, nullptr, nullptr, nullptr);
  gemm_bt_kernel<0><<<dim3(8,64),  256, 0, stream>>>(H1,  W2t, b2, F2, 8192, 1024, 4096, 1.f);
  addln_kernel<<<8192, 256, 0, stream>>>(F2, S1F, g2, be2, (float*)d_out, (bf16*)nullptr);
}